// Round 11
// baseline (650.909 us; speedup 1.0000x reference)
//
#include <hip/hip_runtime.h>
#include <math.h>

// ---------------- problem constants ----------------
// x: (4,512,50,50) f32; conv1_w: (512,512,3,3); heads: 36 loc + 18 score ch
// outputs (f32, concat): rpn_locs 360000 | rpn_scores 180000 @360000 |
//   rois 4800 @540000 | roi_indices 1200 @544800 | anchor 90000 @546000
//
// R17: conv3x3 f16-split MFMA. 1423us. R18: 2-level radix. 1199us.
// R19: alive-only NMS. 994us. R20: crank split. 744us.
// R21 FAILED perf (reg-cap spill). R22: revert. 749us.
// R23 FAILED correctness (conv ULPs -> selection flip). conv FROZEN.
// R24: revert. 749.5us.
// R25: sup word-major: -3us (staging was L2-resident; chain was the cost).
// R26: nms deferred emission + prep wave-aggregated atomics. 613us.
// R27: latency fixes for the tiny-grid tail (same pathology as crank/nms):
//  (a) thresh/thresh2 class sums: was 64-cache-lines-per-load (lanes stride
//      1KB) over a cross-XCD histogram; now coalesced uint4 loads + shfl_xor
//      wave reduce (integer sums exact -> csum bit-identical).
//  (b) cscan: 88 serial global round-trips -> one wave per n, shfl_up
//      prefix scan (exact integer prefix).
// All integer-exact; outputs bit-identical. Everything else unchanged.

typedef _Float16 f16x8 __attribute__((ext_vector_type(8)));
typedef float f32x4 __attribute__((ext_vector_type(4)));

// ======================= W pre-split: f32 -> 2x f16, frag-coalesced ========
__global__ __launch_bounds__(256) void wsplit_kernel(
    const float* __restrict__ wg, _Float16* __restrict__ whi,
    _Float16* __restrict__ wlo)
{
  const int oc = blockIdx.x;
  __shared__ float wb[4608];
  for (int e = threadIdx.x; e < 4608; e += 256) wb[e] = wg[(size_t)oc * 4608 + e];
  __syncthreads();
  const int ochi = oc >> 4, m = oc & 15;
  for (int e = threadIdx.x; e < 4608; e += 256) {
    int tap = e / 512, ic = e & 511;
    float v = wb[ic * 9 + tap] * 256.f;   // exact scale 2^8
    _Float16 h = (_Float16)v;             // RNE
    float r = v - (float)h;               // exact residual
    _Float16 l = (_Float16)r;
    int icg = ic >> 3, icl = ic & 7;
    size_t idx = ((((size_t)ochi * 9 + tap) * 64 + icg) * 16 + m) * 8 + icl;
    whi[idx] = h;
    wlo[idx] = l;
  }
}

// ======================= X transpose to [n][y][x][ic] f32, scaled x16 ======
__global__ __launch_bounds__(256) void xt_kernel(
    const float* __restrict__ xg, float* __restrict__ xt)
{
  const int y = blockIdx.x, n = blockIdx.y;
  __shared__ float tb[128][52];
  for (int icc = 0; icc < 4; icc++) {
    __syncthreads();
    for (int e = threadIdx.x; e < 128 * 50; e += 256) {
      int icL = e / 50, xx = e - icL * 50;
      tb[icL][xx] = 16.f * xg[(((size_t)n * 512 + icc * 128 + icL) * 50 + y) * 50 + xx];
    }
    __syncthreads();
    for (int e = threadIdx.x; e < 50 * 128; e += 256) {
      int xx = e >> 7, icL = e & 127;
      xt[(((size_t)n * 50 + y) * 50 + xx) * 512 + icc * 128 + icL] = tb[icL][xx];
    }
  }
}

// ======================= conv 3x3 via f16-split MFMA (FROZEN) ==============
#define XSLOTS 66
#define PADIC  40

__global__ __launch_bounds__(256, 2) void conv_f16_kernel(
    const float* __restrict__ xt, const _Float16* __restrict__ whi,
    const _Float16* __restrict__ wlo, const float* __restrict__ bg,
    float* __restrict__ featF)
{
  const int y0 = blockIdx.x, ocb = blockIdx.y, n = blockIdx.z;
  const int t = threadIdx.x;
  const int lane = t & 63, wv = t >> 6;
  const int c16 = lane & 15, g = lane >> 4;

  __shared__ _Float16 sX[2][2][3][XSLOTS][PADIC];  // [buf][split][row][xslot][ic]

  for (int e = t; e < (int)(sizeof(sX) / 4); e += 256) ((float*)sX)[e] = 0.f;

  int gbase[3], grw[3], gxs[3], gig[3];
  bool gok[3];
  #pragma unroll
  for (int k = 0; k < 3; k++) {
    int gg = t + k * 256;
    bool ok = gg < 624;
    int row = ok ? gg / 208 : 0;
    int rem = ok ? gg - row * 208 : 0;
    int xs = rem >> 2, ig = rem & 3;
    int yy = y0 + row - 1, xc = xs - 1;
    bool val = ok && yy >= 0 && yy < 50 && xc >= 0 && xc < 50;
    grw[k] = row; gxs[k] = xs; gig[k] = ig; gok[k] = ok;
    gbase[k] = val ? ((((n * 50 + yy) * 50 + xc) << 9) + ig * 8) : -1;
  }

  float4 xr[3][2];
  auto LOADX = [&](int cc) {
    const int ic0 = cc * 32;
    #pragma unroll
    for (int k = 0; k < 3; k++) {
      if (gbase[k] >= 0) {
        const float4* p = (const float4*)(xt + gbase[k] + ic0);
        xr[k][0] = p[0];
        xr[k][1] = p[1];
      } else {
        xr[k][0] = make_float4(0.f, 0.f, 0.f, 0.f);
        xr[k][1] = make_float4(0.f, 0.f, 0.f, 0.f);
      }
    }
  };
  auto WRITEX = [&](int buf) {
    #pragma unroll
    for (int k = 0; k < 3; k++) {
      if (!gok[k]) continue;
      float v[8] = {xr[k][0].x, xr[k][0].y, xr[k][0].z, xr[k][0].w,
                    xr[k][1].x, xr[k][1].y, xr[k][1].z, xr[k][1].w};
      f16x8 h8, l8;
      #pragma unroll
      for (int j = 0; j < 8; j++) {
        _Float16 h = (_Float16)v[j];   // RNE
        float r = v[j] - (float)h;     // exact
        h8[j] = h;
        l8[j] = (_Float16)r;
      }
      *(f16x8*)&sX[buf][0][grw[k]][gxs[k]][gig[k] * 8] = h8;
      *(f16x8*)&sX[buf][1][grw[k]][gxs[k]][gig[k] * 8] = l8;
    }
  };

  f16x8 Ah[2][4], Al[2][4];
  const int ochiB = ocb * 16 + wv * 4;
  auto LOADA = [&](int par, int tap, int cc) {
    #pragma unroll
    for (int os = 0; os < 4; os++) {
      size_t idx = ((((size_t)(ochiB + os) * 9 + tap) * 64 + cc * 4 + g) * 16 + c16) * 8;
      Ah[par][os] = *(const f16x8*)(whi + idx);
      Al[par][os] = *(const f16x8*)(wlo + idx);
    }
  };

  __syncthreads();          // zero-fill visible before staging
  LOADX(0);
  WRITEX(0);
  LOADA(0, 0, 0);

  f32x4 acc[4][4];
  #pragma unroll
  for (int os = 0; os < 4; os++)
    #pragma unroll
    for (int nt = 0; nt < 4; nt++) acc[os][nt] = (f32x4){0.f, 0.f, 0.f, 0.f};

  __syncthreads();

  for (int cc = 0; cc < 16; cc++) {
    const int buf = cc & 1;
    if (cc < 15) LOADX(cc + 1);          // issue global loads early (T14)
    #pragma unroll
    for (int tap = 0; tap < 9; tap++) {
      const int cur = tap & 1;
      if (tap < 8) LOADA(cur ^ 1, tap + 1, cc);
      else if (cc < 15) LOADA(1, 0, cc + 1);
      const int ky = tap / 3, kx = tap - ky * 3;
      #pragma unroll
      for (int nt = 0; nt < 4; nt++) {
        const int xsl = nt * 16 + c16 + kx;   // x = px + kx - 1, slot = x+1
        f16x8 bh = *(const f16x8*)&sX[buf][0][ky][xsl][g * 8];
        f16x8 bl = *(const f16x8*)&sX[buf][1][ky][xsl][g * 8];
        #pragma unroll
        for (int os = 0; os < 4; os++) {
          acc[os][nt] = __builtin_amdgcn_mfma_f32_16x16x32_f16(Ah[cur][os], bh, acc[os][nt], 0, 0, 0);
          acc[os][nt] = __builtin_amdgcn_mfma_f32_16x16x32_f16(Ah[cur][os], bl, acc[os][nt], 0, 0, 0);
          acc[os][nt] = __builtin_amdgcn_mfma_f32_16x16x32_f16(Al[cur][os], bh, acc[os][nt], 0, 0, 0);
        }
      }
      if (tap == 8) {  // restore parity: next chunk's tap0 sits in slot 1
        #pragma unroll
        for (int os = 0; os < 4; os++) { Ah[0][os] = Ah[1][os]; Al[0][os] = Al[1][os]; }
      }
    }
    if (cc < 15) WRITEX(buf ^ 1);
    __syncthreads();
  }

  // epilogue: descale 2^-12 (W x256 * X x16), bias, relu.
  const int ocwbase = ocb * 256 + wv * 64;
  #pragma unroll
  for (int nt = 0; nt < 4; nt++) {
    const int px = nt * 16 + c16;
    if (px < 50) {
      #pragma unroll
      for (int os = 0; os < 4; os++) {
        #pragma unroll
        for (int i = 0; i < 4; i++) {
          const int oc = ocwbase + os * 16 + g * 4 + i;
          featF[(((size_t)n * 512 + oc) * 50 + y0) * 50 + px] =
              fmaxf(acc[os][nt][i] * (1.f / 4096.f) + bg[oc], 0.f);
        }
      }
    }
  }
}

// ======================= 1x1 heads (loc 36 + score 18), f64, DETERMINISTIC ===
__global__ __launch_bounds__(256) void heads_kernel(
    const float* __restrict__ featF,
    const float* __restrict__ loc_w, const float* __restrict__ loc_b,
    const float* __restrict__ score_w, const float* __restrict__ score_b,
    double* __restrict__ locD, double* __restrict__ scoreD,
    float* __restrict__ out)
{
  const int p = blockIdx.x * 256 + threadIdx.x;
  const int ocg = blockIdx.y;
  const int n = blockIdx.z;
  const bool pv = (p < 2500);
  const int pp = pv ? p : 0;
  const float* fbase = featF + (size_t)n * 512 * 2500 + pp;

  __shared__ float wsh[8 * 512];
  double bias[8];
  #pragma unroll
  for (int jj = 0; jj < 8; jj++) {
    int oc = ocg * 8 + jj;
    int occ = (oc < 54) ? oc : 0;
    bias[jj] = (occ < 36) ? (double)loc_b[occ] : (double)score_b[occ - 36];
  }
  for (int e = threadIdx.x; e < 8 * 512; e += 256) {
    int jj = e >> 9, c = e & 511;
    int oc = ocg * 8 + jj;
    int occ = (oc < 54) ? oc : 0;
    wsh[e] = (occ < 36) ? loc_w[(size_t)occ * 512 + c]
                        : score_w[(size_t)(occ - 36) * 512 + c];
  }
  __syncthreads();

  double acc[8] = {0, 0, 0, 0, 0, 0, 0, 0};
  #pragma unroll 4
  for (int c = 0; c < 512; c++) {
    double f = (double)fbase[(size_t)c * 2500];
    #pragma unroll
    for (int jj = 0; jj < 8; jj++) acc[jj] += f * (double)wsh[jj * 512 + c];
  }
  if (!pv) return;
  #pragma unroll
  for (int jj = 0; jj < 8; jj++) {
    int oc = ocg * 8 + jj;
    if (oc >= 54) break;
    double v = acc[jj] + bias[jj];
    if (oc < 36) {
      locD[(size_t)n * 90000 + (size_t)p * 36 + oc] = v;
      out[(size_t)n * 90000 + (size_t)p * 36 + oc] = (float)v;
    } else {
      scoreD[(size_t)n * 45000 + (size_t)p * 18 + (oc - 36)] = v;
      out[360000 + (size_t)n * 45000 + (size_t)p * 18 + (oc - 36)] = (float)v;
    }
  }
}

// robust scalar decode: harness may deliver python ints as int32 or float32
__device__ inline double decode_dim(const int* p) {
  int v = p[0];
  if (v > 0 && v < 1000000) return (double)v;
  return (double)__int_as_float(v);
}

// ======== zero hist/hist2/sValid/sBoxD — MUST run after heads (aliases) ======
__global__ void zero_kernel(unsigned* __restrict__ hist, unsigned* __restrict__ hist2,
                            int* __restrict__ sValid, double* __restrict__ sBoxD)
{
  const int i = blockIdx.x * 256 + threadIdx.x;
  if (i < 262144) { hist[i] = 0u; hist2[i] = 0u; }
  if (i < 12000) sValid[i] = 0;
  if (i < 48000) sBoxD[i] = 0.0;
}

// ======================= anchors + loc2bbox + clip + valid + fg (f64) ========
// R26: histogram atomics wave-aggregated (scores cluster -> same-bin
// contention). One atomicAdd(+popcount) per distinct key per wave.
__global__ void prep_kernel(const double* __restrict__ locD,
                            const double* __restrict__ scoreD,
                            const int* __restrict__ img_h_p, const int* __restrict__ img_w_p,
                            double* __restrict__ roiD, double* __restrict__ selD,
                            unsigned* __restrict__ hist, float* __restrict__ d_out)
{
  const int i = blockIdx.x * 256 + threadIdx.x;
  const int n = blockIdx.y;
  if (i >= 22500) return;
  const int p = i / 9, ab = i - p * 9;
  const int y = p / 50, x = p - y * 50;
  const int ri = ab / 3, sidx = ab - ri * 3;
  const double rr = (ri == 0) ? 0.5 : (ri == 1 ? 1.0 : 2.0);
  const double sc = (sidx == 0) ? 8.0 : (sidx == 1 ? 16.0 : 32.0);
  const double hh = 16.0 * sc * sqrt(rr);
  const double wd = 16.0 * sc * sqrt(1.0 / rr);
  const float bx1 = (float)(8.0 - wd * 0.5), by1 = (float)(8.0 - hh * 0.5);
  const float bx2 = (float)(8.0 + wd * 0.5), by2 = (float)(8.0 + hh * 0.5);
  const float sxf = (float)(x * 16), syf = (float)(y * 16);
  const float ax1 = bx1 + sxf, ay1 = by1 + syf, ax2 = bx2 + sxf, ay2 = by2 + syf;
  if (n == 0) {
    ((float4*)(d_out + 546000))[i] = make_float4(ax1, ay1, ax2, ay2);
  }
  const double l0 = locD[(size_t)n * 90000 + (size_t)i * 4 + 0];
  const double l1 = locD[(size_t)n * 90000 + (size_t)i * 4 + 1];
  const double l2 = locD[(size_t)n * 90000 + (size_t)i * 4 + 2];
  const double l3 = locD[(size_t)n * 90000 + (size_t)i * 4 + 3];
  const double s0 = scoreD[(size_t)n * 45000 + (size_t)i * 2 + 0];
  const double s1 = scoreD[(size_t)n * 45000 + (size_t)i * 2 + 1];
  const double aw = (double)ax2 - (double)ax1, ah = (double)ay2 - (double)ay1;
  const double acx = (double)ax1 + 0.5 * aw, acy = (double)ay1 + 0.5 * ah;
  const double cx = l0 * aw + acx, cy = l1 * ah + acy;
  const double ww = exp(l2) * aw, hh2 = exp(l3) * ah;
  double x1 = cx - 0.5 * ww, y1 = cy - 0.5 * hh2;
  double x2 = cx + 0.5 * ww, y2 = cy + 0.5 * hh2;
  const double fw = decode_dim(img_w_p), fh = decode_dim(img_h_p);
  x1 = fmin(fmax(x1, 0.0), fw); x2 = fmin(fmax(x2, 0.0), fw);
  y1 = fmin(fmax(y1, 0.0), fh); y2 = fmin(fmax(y2, 0.0), fh);
  const bool valid = (x2 - x1 + 1.0 >= 16.0) && (y2 - y1 + 1.0 >= 16.0);
  const double m = fmax(s0, s1);
  const double e0 = exp(s0 - m), e1 = exp(s1 - m);
  const double fg = e1 / (e0 + e1);
  double* rb = roiD + ((size_t)n * 22500 + i) * 4;
  rb[0] = x1; rb[1] = y1; rb[2] = x2; rb[3] = y2;
  selD[(size_t)n * 22500 + i] = valid ? fg : -INFINITY;
  // fg in (0,1): positive f64 -> bits order == value order
  const unsigned key = (unsigned)((unsigned long long)__double_as_longlong(fg) >> 48);
  const int lane = threadIdx.x & 63;
  unsigned long long act = __ballot(valid);
  while (act) {
    const int leader = __ffsll(act) - 1;
    const unsigned k0 = (unsigned)__shfl((int)key, leader);
    const unsigned long long same = __ballot(valid && key == k0);
    if (lane == leader)
      atomicAdd(&hist[n * 65536 + k0], (unsigned)__popcll(same));
    act &= ~same;
  }
}

// ======================= threshold L1: largest key covering top-3000 ========
// R27: class sums via coalesced uint4 loads + shfl_xor wave reduce (wave w
// covers classes [w*64, w*64+64)). Integer sums exact -> csum bit-identical.
__global__ __launch_bounds__(256) void thresh_kernel(
    const unsigned* __restrict__ hist, unsigned* __restrict__ thrP,
    unsigned* __restrict__ cntAbove)
{
  const int n = blockIdx.x;
  const int t = threadIdx.x;
  const int lane = t & 63, w = t >> 6;
  __shared__ unsigned csum[256];
  __shared__ unsigned hv[256];
  __shared__ int cstar;
  __shared__ unsigned sufS;
  const unsigned* h = hist + (size_t)n * 65536;
  for (int cls = 0; cls < 64; cls++) {
    const int c = w * 64 + cls;
    const uint4 q = *(const uint4*)(h + c * 256 + lane * 4);
    unsigned s = q.x + q.y + q.z + q.w;
    #pragma unroll
    for (int off = 1; off < 64; off <<= 1) s += (unsigned)__shfl_xor((int)s, off);
    if (lane == 0) csum[c] = s;
  }
  __syncthreads();
  if (t == 0) {
    unsigned suf = 0; int cs = -1;
    for (int c = 255; c >= 0; c--) {
      if (suf + csum[c] >= 3000u) { cs = c; break; }
      suf += csum[c];
    }
    cstar = cs; sufS = suf;
  }
  __syncthreads();
  const int cs = cstar;
  if (cs >= 0) hv[t] = h[cs * 256 + t];
  __syncthreads();
  if (t == 0) {
    unsigned Tkey = 0, above = 0;
    if (cs >= 0) {
      unsigned suf = sufS;
      for (int v = 255; v >= 0; v--) {
        if (suf + hv[v] >= 3000u) { Tkey = (unsigned)(cs * 256 + v); above = suf; break; }
        suf += hv[v];
      }
    }
    thrP[n] = Tkey;        // 0 if <3000 valid -> all valid become candidates
    cntAbove[n] = above;   // strictly < 3000 by construction
  }
}

// ============ L2 refinement: histogram bits 47:32 within threshold class ====
__global__ void hist2_kernel(const double* __restrict__ selD,
                             const unsigned* __restrict__ thrP,
                             unsigned* __restrict__ hist2)
{
  const int i = blockIdx.x * 256 + threadIdx.x;
  const int n = blockIdx.y;
  if (i >= 22500) return;
  double s = selD[(size_t)n * 22500 + i];
  if (!(s > -INFINITY)) return;
  unsigned long long b = (unsigned long long)__double_as_longlong(s);
  if ((unsigned)(b >> 48) == thrP[n]) {
    unsigned key2 = (unsigned)(b >> 32) & 0xFFFFu;
    atomicAdd(&hist2[n * 65536 + key2], 1u);   // keys well-spread: low contention
  }
}

// thresh2: largest key2 s.t. cntAbove + suffix2 >= 3000 (0 if class empty)
// R27: same coalesced class-sum restructure as thresh.
__global__ __launch_bounds__(256) void thresh2_kernel(
    const unsigned* __restrict__ hist2, const unsigned* __restrict__ cntAbove,
    unsigned* __restrict__ thr2P)
{
  const int n = blockIdx.x;
  const int t = threadIdx.x;
  const int lane = t & 63, w = t >> 6;
  __shared__ unsigned csum[256];
  __shared__ unsigned hv[256];
  __shared__ int cstar;
  __shared__ unsigned sufS;
  const unsigned* h = hist2 + (size_t)n * 65536;
  const unsigned target = 3000u - cntAbove[n];   // >= 1
  for (int cls = 0; cls < 64; cls++) {
    const int c = w * 64 + cls;
    const uint4 q = *(const uint4*)(h + c * 256 + lane * 4);
    unsigned s = q.x + q.y + q.z + q.w;
    #pragma unroll
    for (int off = 1; off < 64; off <<= 1) s += (unsigned)__shfl_xor((int)s, off);
    if (lane == 0) csum[c] = s;
  }
  __syncthreads();
  if (t == 0) {
    unsigned suf = 0; int cs = -1;
    for (int c = 255; c >= 0; c--) {
      if (suf + csum[c] >= target) { cs = c; break; }
      suf += csum[c];
    }
    cstar = cs; sufS = suf;
  }
  __syncthreads();
  const int cs = cstar;
  if (cs >= 0) hv[t] = h[cs * 256 + t];
  __syncthreads();
  if (t == 0) {
    unsigned T2 = 0;
    if (cs >= 0) {
      unsigned suf = sufS;
      for (int v = 255; v >= 0; v--) {
        suf += hv[v];
        if (suf >= target) { T2 = (unsigned)(cs * 256 + v); break; }
      }
    }
    thr2P[n] = T2;   // 0 if class can't reach target (e.g. <3000 valid total)
  }
}

// ============ deterministic 2-phase compaction (no atomics) =================
__device__ inline bool cand_flag(const double* __restrict__ selD,
                                 const unsigned* __restrict__ thrP,
                                 const unsigned* __restrict__ thr2P,
                                 int n, int i, double* sOut) {
  double s = selD[(size_t)n * 22500 + i];
  *sOut = s;
  if (!(s > -INFINITY)) return false;
  unsigned long long b = (unsigned long long)__double_as_longlong(s);
  unsigned key = (unsigned)(b >> 48);
  unsigned T = thrP[n];
  if (key != T) return key > T;
  return ((unsigned)(b >> 32) & 0xFFFFu) >= thr2P[n];
}

// phase 1: per-block candidate counts
__global__ __launch_bounds__(256) void ccount_kernel(
    const double* __restrict__ selD, const unsigned* __restrict__ thrP,
    const unsigned* __restrict__ thr2P, unsigned* __restrict__ blkCnt)
{
  const int i = blockIdx.x * 256 + threadIdx.x;
  const int n = blockIdx.y;
  double s;
  bool f = (i < 22500) && cand_flag(selD, thrP, thr2P, n, i, &s);
  unsigned long long b = __ballot(f);
  __shared__ unsigned wc[4];
  const int wv = threadIdx.x >> 6, lane = threadIdx.x & 63;
  if (lane == 0) wc[wv] = (unsigned)__popcll(b);
  __syncthreads();
  if (threadIdx.x == 0)
    blkCnt[n * 88 + blockIdx.x] = wc[0] + wc[1] + wc[2] + wc[3];
}

// phase 2 (R27): one wave per n; 64-lane shfl_up exclusive prefix over 88
// entries (64 + 24). Exact integer prefix -> blkOff/mOut bit-identical.
__global__ __launch_bounds__(256) void cscan_kernel(
    const unsigned* __restrict__ blkCnt, unsigned* __restrict__ blkOff,
    unsigned* __restrict__ mOut)
{
  const int n = threadIdx.x >> 6;
  const int lane = threadIdx.x & 63;
  const int e0 = (int)blkCnt[n * 88 + lane];
  const int e1 = (lane < 24) ? (int)blkCnt[n * 88 + 64 + lane] : 0;
  int s0 = e0;
  #pragma unroll
  for (int off = 1; off < 64; off <<= 1) {
    int t2 = __shfl_up(s0, off);
    if (lane >= off) s0 += t2;
  }
  const int tot0 = __shfl(s0, 63);
  int s1 = e1;
  #pragma unroll
  for (int off = 1; off < 64; off <<= 1) {
    int t2 = __shfl_up(s1, off);
    if (lane >= off) s1 += t2;
  }
  const int tot1 = __shfl(s1, 63);
  blkOff[n * 88 + lane] = (unsigned)(s0 - e0);
  if (lane < 24) blkOff[n * 88 + 64 + lane] = (unsigned)(tot0 + s1 - e1);
  if (lane == 0) mOut[n] = (unsigned)(tot0 + tot1);
}

// phase 3: index-ordered scatter at deterministic offsets
__global__ __launch_bounds__(256) void cscatter_kernel(
    const double* __restrict__ selD, const unsigned* __restrict__ thrP,
    const unsigned* __restrict__ thr2P, const unsigned* __restrict__ blkOff,
    int* __restrict__ candIdx, double* __restrict__ candS)
{
  const int i = blockIdx.x * 256 + threadIdx.x;
  const int n = blockIdx.y;
  double s = 0.0;
  bool f = (i < 22500) && cand_flag(selD, thrP, thr2P, n, i, &s);
  unsigned long long b = __ballot(f);
  const int wv = threadIdx.x >> 6, lane = threadIdx.x & 63;
  __shared__ unsigned wc[4];
  if (lane == 0) wc[wv] = (unsigned)__popcll(b);
  __syncthreads();
  unsigned woff = 0;
  for (int w = 0; w < wv; w++) woff += wc[w];
  unsigned lpre = (unsigned)__popcll(b & ((1ull << lane) - 1ull));
  if (f) {
    unsigned pos = blkOff[n * 88 + blockIdx.x] + woff + lpre;
    candIdx[(size_t)n * 22500 + pos] = i;
    candS[(size_t)n * 22500 + pos] = s;
  }
}

// ============ exact rank among candidates, j-axis split 12 ways =============
#define RCHUNKS 12
#define RSTRIDE 22528

__global__ __launch_bounds__(256) void crank1_kernel(
    const unsigned* __restrict__ mOut, const int* __restrict__ candIdx,
    const double* __restrict__ candS, int* __restrict__ partialR)
{
  const int n = blockIdx.z;
  const int m = (int)mOut[n];
  if ((int)(blockIdx.x * 256) >= m) return;   // block-uniform early exit
  const int c = blockIdx.y;
  const int tid = blockIdx.x * 256 + threadIdx.x;
  const bool act = (tid < m);
  const double si = act ? candS[(size_t)n * 22500 + tid] : 0.0;
  const int ii = act ? candIdx[(size_t)n * 22500 + tid] : 0x7fffffff;
  const int jlo = (int)(((long long)c * m) / RCHUNKS);
  const int jhi = (int)(((long long)(c + 1) * m) / RCHUNKS);
  __shared__ double sv[256];
  __shared__ int siv[256];
  int rank = 0;
  for (int j0 = jlo; j0 < jhi; j0 += 256) {
    __syncthreads();
    const int jl = j0 + threadIdx.x;
    if (jl < jhi) {
      sv[threadIdx.x] = candS[(size_t)n * 22500 + jl];
      siv[threadIdx.x] = candIdx[(size_t)n * 22500 + jl];
    }
    __syncthreads();
    const int lim = (jhi - j0 < 256) ? (jhi - j0) : 256;
    #pragma unroll 8
    for (int k = 0; k < lim; k++) {
      const double sj = sv[k];
      const int ij = siv[k];
      rank += ((sj > si) || (sj == si && ij < ii)) ? 1 : 0;
    }
  }
  if (act) partialR[((size_t)n * RCHUNKS + c) * RSTRIDE + tid] = rank;
}

__global__ __launch_bounds__(256) void crank2_kernel(
    const unsigned* __restrict__ mOut, const int* __restrict__ candIdx,
    const int* __restrict__ partialR, const double* __restrict__ roiD,
    double* __restrict__ sBoxD, int* __restrict__ sValid)
{
  const int n = blockIdx.y;
  const int m = (int)mOut[n];
  const int tid = blockIdx.x * 256 + threadIdx.x;
  if (tid >= m) return;
  int rank = 0;
  #pragma unroll
  for (int c = 0; c < RCHUNKS; c++)
    rank += partialR[((size_t)n * RCHUNKS + c) * RSTRIDE + tid];
  if (rank < 3000) {
    const int ii = candIdx[(size_t)n * 22500 + tid];
    const double* rb = roiD + ((size_t)n * 22500 + ii) * 4;
    double* db = sBoxD + ((size_t)n * 3000 + rank) * 4;
    db[0] = rb[0]; db[1] = rb[1]; db[2] = rb[2]; db[3] = rb[3];
    sValid[n * 3000 + rank] = 1;
  }
}

// ======================= NMS phase A: suppression bitmask (f64 IoU) ==========
// sup layout WORD-MAJOR (R25): sup[((n*47 + wj)*3008) + i]; coalesced stores.
__global__ void supmat_kernel(const double* __restrict__ sBoxD,
                              unsigned long long* __restrict__ sup)
{
  const int wj = blockIdx.x, ig = blockIdx.y, n = blockIdx.z;
  const int lane = threadIdx.x;
  const int i = ig * 64 + lane;
  unsigned long long* dst = sup + ((size_t)n * 47 + wj) * 3008;
  if (wj < ig) {                       // strictly below diagonal: all zero
    if (i < 3000) dst[i] = 0ull;
    return;
  }
  __shared__ double jb[64][4];
  const int j0 = wj * 64;
  {
    int j = j0 + lane;
    if (j < 3000) {
      const double* b = sBoxD + ((size_t)n * 3000 + j) * 4;
      jb[lane][0] = b[0]; jb[lane][1] = b[1]; jb[lane][2] = b[2]; jb[lane][3] = b[3];
    } else {
      jb[lane][0] = 0; jb[lane][1] = 0; jb[lane][2] = 0; jb[lane][3] = 0;
    }
  }
  __syncthreads();
  if (i >= 3000) return;
  const double* bi = sBoxD + ((size_t)n * 3000 + i) * 4;
  const double bx1 = bi[0], by1 = bi[1], bx2 = bi[2], by2 = bi[3];
  const double ai = (bx2 - bx1) * (by2 - by1);
  unsigned long long msk = 0;
  #pragma unroll 2
  for (int tt = 0; tt < 64; tt++) {
    const int j = j0 + tt;
    const double jx1 = jb[tt][0], jy1 = jb[tt][1], jx2 = jb[tt][2], jy2 = jb[tt][3];
    double iw = fmax(fmin(bx2, jx2) - fmax(bx1, jx1), 0.0);
    double ih = fmax(fmin(by2, jy2) - fmax(by1, jy1), 0.0);
    double inter = iw * ih;
    double aj = (jx2 - jx1) * (jy2 - jy1);
    double iou = inter / (ai + aj - inter + 1e-9);
    if (iou > 0.7 && j > i && j < 3000) msk |= (1ull << tt);
  }
  dst[i] = msk;
}

// ======================= NMS phase B: alive-only scan, early stop at 300 =====
// R26: serial kept-loop touches ONLY LDS + shfl; box emission deferred.
__global__ __launch_bounds__(64) void nms_scan_kernel(
    const double* __restrict__ sBoxD,
    const int* __restrict__ sValid,
    const unsigned long long* __restrict__ sup,
    float* __restrict__ out)
{
  const int n = blockIdx.x;
  const int lane = threadIdx.x;
  unsigned long long alive = 0;
  for (int w = 0; w < 47; w++) {
    int idx = w * 64 + lane;
    int v = (idx < 3000) ? sValid[(size_t)n * 3000 + idx] : 0;
    unsigned long long bm = __ballot(v != 0);
    if (lane == w) alive = bm;
  }
  const unsigned long long* sbase = sup + (size_t)n * 47 * 3008;

  __shared__ unsigned long long rows[2][64][49];
  __shared__ int keptIdx[304];
  unsigned long long stg[47];

  auto STAGE_LOAD = [&](int w) {
    const unsigned long long* src = sbase + w * 64 + lane;
    #pragma unroll
    for (int k = 0; k < 47; k++) stg[k] = src[(size_t)k * 3008];
  };
  auto STAGE_WRITE = [&](int buf) {
    #pragma unroll
    for (int k = 0; k < 47; k++) rows[buf][lane][k] = stg[k];
  };

  STAGE_LOAD(0);
  STAGE_WRITE(0);
  __syncthreads();
  STAGE_LOAD(1);

  int kept = 0;
  for (int w = 0; w < 47 && kept < 300; w++) {
    const int buf = w & 1;
    unsigned long long t = __shfl(alive, w);
    while (t != 0ull && kept < 300) {
      const int b = __ffsll(t) - 1;
      const int i = w * 64 + b;
      unsigned long long row = (lane < 47) ? rows[buf][b][lane] : 0ull;
      alive &= ~row;
      if (lane == 0) keptIdx[kept] = i;    // ds_write: off the serial chain
      kept++;
      const unsigned long long hi = (b == 63) ? 0ull : (~0ull << (b + 1));
      t = __shfl(alive, w) & hi;
    }
    if (w + 1 < 47) {
      STAGE_WRITE(buf ^ 1);
      __syncthreads();
      if (w + 2 < 47) STAGE_LOAD(w + 2);
    }
  }
  __syncthreads();                         // keptIdx visible to all lanes

  float4* rois4 = (float4*)(out + 540000);
  for (int r = lane; r < kept; r += 64) {
    const int i = keptIdx[r];
    const double* bb = sBoxD + ((size_t)n * 3000 + i) * 4;
    rois4[n * 300 + r] = make_float4((float)bb[0], (float)bb[1],
                                     (float)bb[2], (float)bb[3]);
  }
  for (int k = kept + lane; k < 300; k += 64)
    rois4[n * 300 + k] = make_float4(0, 0, 0, 0);
  for (int k = lane; k < 300; k += 64)
    out[544800 + n * 300 + k] = (float)n;
}

// ======================= launch =======================
extern "C" void kernel_launch(void* const* d_in, const int* in_sizes, int n_in,
                              void* d_out, int out_size, void* d_ws, size_t ws_size,
                              hipStream_t stream) {
  const float* x        = (const float*)d_in[0];
  const float* conv1_w  = (const float*)d_in[1];
  const float* conv1_b  = (const float*)d_in[2];
  const float* loc_w    = (const float*)d_in[3];
  const float* loc_b    = (const float*)d_in[4];
  const float* score_w  = (const float*)d_in[5];
  const float* score_b  = (const float*)d_in[6];
  const int*   img_h    = (const int*)d_in[7];
  const int*   img_w    = (const int*)d_in[8];
  float* out = (float*)d_out;
  char* ws = (char*)d_ws;

  float*    featF = (float*)(ws);                       // [0, 20,480,000)
  _Float16* Whi   = (_Float16*)(ws + 20480000);         // +4,718,592
  _Float16* Wlo   = (_Float16*)(ws + 25198592);         // +4,718,592
  float*    Xt    = (float*)(ws + 29917184);            // +10,240,000 -> 40,157,184
  double*   locD   = (double*)(ws + 20480000);          // +2,880,000 (over Whi, dead)
  double*   scoreD = (double*)(ws + 23360000);          // +1,440,000 -> 24,800,000
  double* roiD   = (double*)(ws);                  // [0, 2,880,000)
  double* selD   = (double*)(ws + 2880000);        // +720,000
  double* sBoxD  = (double*)(ws + 3600000);        // +384,000
  int*    sValid = (int*)(ws + 4000000);           // +48,000
  unsigned long long* sup = (unsigned long long*)(ws + 4100000);  // +4,524,032 (word-major) -> 8,624,032
  unsigned* hist   = (unsigned*)(ws + 8700000);    // +1,048,576
  unsigned* blkCnt = (unsigned*)(ws + 9750000);    // +1,408
  unsigned* blkOff = (unsigned*)(ws + 9752000);    // +1,408
  unsigned* mOut   = (unsigned*)(ws + 9754000);    // +16
  unsigned* thrP   = (unsigned*)(ws + 9755000);    // +16
  unsigned* cntAb  = (unsigned*)(ws + 9756000);    // +16
  unsigned* thr2P  = (unsigned*)(ws + 9757000);    // +16
  int*      candIdx= (int*)(ws + 9760000);         // +360,000
  double*   candS  = (double*)(ws + 10200000);     // +720,000 -> 10,920,000
  unsigned* hist2  = (unsigned*)(ws + 10920000);   // +1,048,576 -> 11,968,576
  int*      partialR = (int*)(ws + 12000000);      // +4,325,376 -> 16,325,376

  wsplit_kernel<<<512, 256, 0, stream>>>(conv1_w, Whi, Wlo);
  xt_kernel<<<dim3(50, 4), 256, 0, stream>>>(x, Xt);
  conv_f16_kernel<<<dim3(50, 2, 4), 256, 0, stream>>>(Xt, Whi, Wlo, conv1_b, featF);
  heads_kernel<<<dim3(10, 7, 4), 256, 0, stream>>>(featF, loc_w, loc_b, score_w, score_b,
                                                   locD, scoreD, out);
  zero_kernel<<<1024, 256, 0, stream>>>(hist, hist2, sValid, sBoxD);  // after heads!
  prep_kernel<<<dim3(88, 4), 256, 0, stream>>>(locD, scoreD, img_h, img_w,
                                               roiD, selD, hist, out);
  thresh_kernel<<<4, 256, 0, stream>>>(hist, thrP, cntAb);
  hist2_kernel<<<dim3(88, 4), 256, 0, stream>>>(selD, thrP, hist2);
  thresh2_kernel<<<4, 256, 0, stream>>>(hist2, cntAb, thr2P);
  ccount_kernel<<<dim3(88, 4), 256, 0, stream>>>(selD, thrP, thr2P, blkCnt);
  cscan_kernel<<<1, 256, 0, stream>>>(blkCnt, blkOff, mOut);
  cscatter_kernel<<<dim3(88, 4), 256, 0, stream>>>(selD, thrP, thr2P, blkOff, candIdx, candS);
  crank1_kernel<<<dim3(88, RCHUNKS, 4), 256, 0, stream>>>(mOut, candIdx, candS, partialR);
  crank2_kernel<<<dim3(88, 4), 256, 0, stream>>>(mOut, candIdx, partialR, roiD, sBoxD, sValid);
  supmat_kernel<<<dim3(47, 47, 4), 64, 0, stream>>>(sBoxD, sup);
  nms_scan_kernel<<<4, 64, 0, stream>>>(sBoxD, sValid, sup, out);
}

// Round 12
// 614.177 us; speedup vs baseline: 1.0598x; 1.0598x over previous
//
#include <hip/hip_runtime.h>
#include <math.h>

// ---------------- problem constants ----------------
// x: (4,512,50,50) f32; conv1_w: (512,512,3,3); heads: 36 loc + 18 score ch
// outputs (f32, concat): rpn_locs 360000 | rpn_scores 180000 @360000 |
//   rois 4800 @540000 | roi_indices 1200 @544800 | anchor 90000 @546000
//
// R17: conv3x3 f16-split MFMA. 1423us. R18: 2-level radix. 1199us.
// R19: alive-only NMS. 994us. R20: crank split. 744us.
// R21 FAILED perf (reg-cap spill). R22: revert. 749us.
// R23 FAILED correctness (conv ULPs -> selection flip). conv FROZEN.
// R24: revert. 749.5us.
// R25: sup word-major: -3us (staging was L2-resident).
// R26: nms deferred emission + prep wave-aggregated atomics. 613us.
// R27 REGRESSED (651us): thresh "coalescing" replaced independent pipelined
//   per-thread sums (cache-line reuse across k!) with a serial dependent
//   {gather -> 6-shfl} chain per class. LESSON: deserializing traffic must
//   not serialize the latency chain.
// R28: revert thresh/thresh2 to R26 form; KEEP R27's cscan (parallel loads
//   + shfl_up prefix — strictly less serial than 88 global round-trips,
//   integer-exact, verified in R27's passing run). Everything else = R26.

typedef _Float16 f16x8 __attribute__((ext_vector_type(8)));
typedef float f32x4 __attribute__((ext_vector_type(4)));

// ======================= W pre-split: f32 -> 2x f16, frag-coalesced ========
__global__ __launch_bounds__(256) void wsplit_kernel(
    const float* __restrict__ wg, _Float16* __restrict__ whi,
    _Float16* __restrict__ wlo)
{
  const int oc = blockIdx.x;
  __shared__ float wb[4608];
  for (int e = threadIdx.x; e < 4608; e += 256) wb[e] = wg[(size_t)oc * 4608 + e];
  __syncthreads();
  const int ochi = oc >> 4, m = oc & 15;
  for (int e = threadIdx.x; e < 4608; e += 256) {
    int tap = e / 512, ic = e & 511;
    float v = wb[ic * 9 + tap] * 256.f;   // exact scale 2^8
    _Float16 h = (_Float16)v;             // RNE
    float r = v - (float)h;               // exact residual
    _Float16 l = (_Float16)r;
    int icg = ic >> 3, icl = ic & 7;
    size_t idx = ((((size_t)ochi * 9 + tap) * 64 + icg) * 16 + m) * 8 + icl;
    whi[idx] = h;
    wlo[idx] = l;
  }
}

// ======================= X transpose to [n][y][x][ic] f32, scaled x16 ======
__global__ __launch_bounds__(256) void xt_kernel(
    const float* __restrict__ xg, float* __restrict__ xt)
{
  const int y = blockIdx.x, n = blockIdx.y;
  __shared__ float tb[128][52];
  for (int icc = 0; icc < 4; icc++) {
    __syncthreads();
    for (int e = threadIdx.x; e < 128 * 50; e += 256) {
      int icL = e / 50, xx = e - icL * 50;
      tb[icL][xx] = 16.f * xg[(((size_t)n * 512 + icc * 128 + icL) * 50 + y) * 50 + xx];
    }
    __syncthreads();
    for (int e = threadIdx.x; e < 50 * 128; e += 256) {
      int xx = e >> 7, icL = e & 127;
      xt[(((size_t)n * 50 + y) * 50 + xx) * 512 + icc * 128 + icL] = tb[icL][xx];
    }
  }
}

// ======================= conv 3x3 via f16-split MFMA (FROZEN) ==============
#define XSLOTS 66
#define PADIC  40

__global__ __launch_bounds__(256, 2) void conv_f16_kernel(
    const float* __restrict__ xt, const _Float16* __restrict__ whi,
    const _Float16* __restrict__ wlo, const float* __restrict__ bg,
    float* __restrict__ featF)
{
  const int y0 = blockIdx.x, ocb = blockIdx.y, n = blockIdx.z;
  const int t = threadIdx.x;
  const int lane = t & 63, wv = t >> 6;
  const int c16 = lane & 15, g = lane >> 4;

  __shared__ _Float16 sX[2][2][3][XSLOTS][PADIC];  // [buf][split][row][xslot][ic]

  for (int e = t; e < (int)(sizeof(sX) / 4); e += 256) ((float*)sX)[e] = 0.f;

  int gbase[3], grw[3], gxs[3], gig[3];
  bool gok[3];
  #pragma unroll
  for (int k = 0; k < 3; k++) {
    int gg = t + k * 256;
    bool ok = gg < 624;
    int row = ok ? gg / 208 : 0;
    int rem = ok ? gg - row * 208 : 0;
    int xs = rem >> 2, ig = rem & 3;
    int yy = y0 + row - 1, xc = xs - 1;
    bool val = ok && yy >= 0 && yy < 50 && xc >= 0 && xc < 50;
    grw[k] = row; gxs[k] = xs; gig[k] = ig; gok[k] = ok;
    gbase[k] = val ? ((((n * 50 + yy) * 50 + xc) << 9) + ig * 8) : -1;
  }

  float4 xr[3][2];
  auto LOADX = [&](int cc) {
    const int ic0 = cc * 32;
    #pragma unroll
    for (int k = 0; k < 3; k++) {
      if (gbase[k] >= 0) {
        const float4* p = (const float4*)(xt + gbase[k] + ic0);
        xr[k][0] = p[0];
        xr[k][1] = p[1];
      } else {
        xr[k][0] = make_float4(0.f, 0.f, 0.f, 0.f);
        xr[k][1] = make_float4(0.f, 0.f, 0.f, 0.f);
      }
    }
  };
  auto WRITEX = [&](int buf) {
    #pragma unroll
    for (int k = 0; k < 3; k++) {
      if (!gok[k]) continue;
      float v[8] = {xr[k][0].x, xr[k][0].y, xr[k][0].z, xr[k][0].w,
                    xr[k][1].x, xr[k][1].y, xr[k][1].z, xr[k][1].w};
      f16x8 h8, l8;
      #pragma unroll
      for (int j = 0; j < 8; j++) {
        _Float16 h = (_Float16)v[j];   // RNE
        float r = v[j] - (float)h;     // exact
        h8[j] = h;
        l8[j] = (_Float16)r;
      }
      *(f16x8*)&sX[buf][0][grw[k]][gxs[k]][gig[k] * 8] = h8;
      *(f16x8*)&sX[buf][1][grw[k]][gxs[k]][gig[k] * 8] = l8;
    }
  };

  f16x8 Ah[2][4], Al[2][4];
  const int ochiB = ocb * 16 + wv * 4;
  auto LOADA = [&](int par, int tap, int cc) {
    #pragma unroll
    for (int os = 0; os < 4; os++) {
      size_t idx = ((((size_t)(ochiB + os) * 9 + tap) * 64 + cc * 4 + g) * 16 + c16) * 8;
      Ah[par][os] = *(const f16x8*)(whi + idx);
      Al[par][os] = *(const f16x8*)(wlo + idx);
    }
  };

  __syncthreads();          // zero-fill visible before staging
  LOADX(0);
  WRITEX(0);
  LOADA(0, 0, 0);

  f32x4 acc[4][4];
  #pragma unroll
  for (int os = 0; os < 4; os++)
    #pragma unroll
    for (int nt = 0; nt < 4; nt++) acc[os][nt] = (f32x4){0.f, 0.f, 0.f, 0.f};

  __syncthreads();

  for (int cc = 0; cc < 16; cc++) {
    const int buf = cc & 1;
    if (cc < 15) LOADX(cc + 1);          // issue global loads early (T14)
    #pragma unroll
    for (int tap = 0; tap < 9; tap++) {
      const int cur = tap & 1;
      if (tap < 8) LOADA(cur ^ 1, tap + 1, cc);
      else if (cc < 15) LOADA(1, 0, cc + 1);
      const int ky = tap / 3, kx = tap - ky * 3;
      #pragma unroll
      for (int nt = 0; nt < 4; nt++) {
        const int xsl = nt * 16 + c16 + kx;   // x = px + kx - 1, slot = x+1
        f16x8 bh = *(const f16x8*)&sX[buf][0][ky][xsl][g * 8];
        f16x8 bl = *(const f16x8*)&sX[buf][1][ky][xsl][g * 8];
        #pragma unroll
        for (int os = 0; os < 4; os++) {
          acc[os][nt] = __builtin_amdgcn_mfma_f32_16x16x32_f16(Ah[cur][os], bh, acc[os][nt], 0, 0, 0);
          acc[os][nt] = __builtin_amdgcn_mfma_f32_16x16x32_f16(Ah[cur][os], bl, acc[os][nt], 0, 0, 0);
          acc[os][nt] = __builtin_amdgcn_mfma_f32_16x16x32_f16(Al[cur][os], bh, acc[os][nt], 0, 0, 0);
        }
      }
      if (tap == 8) {  // restore parity: next chunk's tap0 sits in slot 1
        #pragma unroll
        for (int os = 0; os < 4; os++) { Ah[0][os] = Ah[1][os]; Al[0][os] = Al[1][os]; }
      }
    }
    if (cc < 15) WRITEX(buf ^ 1);
    __syncthreads();
  }

  // epilogue: descale 2^-12 (W x256 * X x16), bias, relu.
  const int ocwbase = ocb * 256 + wv * 64;
  #pragma unroll
  for (int nt = 0; nt < 4; nt++) {
    const int px = nt * 16 + c16;
    if (px < 50) {
      #pragma unroll
      for (int os = 0; os < 4; os++) {
        #pragma unroll
        for (int i = 0; i < 4; i++) {
          const int oc = ocwbase + os * 16 + g * 4 + i;
          featF[(((size_t)n * 512 + oc) * 50 + y0) * 50 + px] =
              fmaxf(acc[os][nt][i] * (1.f / 4096.f) + bg[oc], 0.f);
        }
      }
    }
  }
}

// ======================= 1x1 heads (loc 36 + score 18), f64, DETERMINISTIC ===
__global__ __launch_bounds__(256) void heads_kernel(
    const float* __restrict__ featF,
    const float* __restrict__ loc_w, const float* __restrict__ loc_b,
    const float* __restrict__ score_w, const float* __restrict__ score_b,
    double* __restrict__ locD, double* __restrict__ scoreD,
    float* __restrict__ out)
{
  const int p = blockIdx.x * 256 + threadIdx.x;
  const int ocg = blockIdx.y;
  const int n = blockIdx.z;
  const bool pv = (p < 2500);
  const int pp = pv ? p : 0;
  const float* fbase = featF + (size_t)n * 512 * 2500 + pp;

  __shared__ float wsh[8 * 512];
  double bias[8];
  #pragma unroll
  for (int jj = 0; jj < 8; jj++) {
    int oc = ocg * 8 + jj;
    int occ = (oc < 54) ? oc : 0;
    bias[jj] = (occ < 36) ? (double)loc_b[occ] : (double)score_b[occ - 36];
  }
  for (int e = threadIdx.x; e < 8 * 512; e += 256) {
    int jj = e >> 9, c = e & 511;
    int oc = ocg * 8 + jj;
    int occ = (oc < 54) ? oc : 0;
    wsh[e] = (occ < 36) ? loc_w[(size_t)occ * 512 + c]
                        : score_w[(size_t)(occ - 36) * 512 + c];
  }
  __syncthreads();

  double acc[8] = {0, 0, 0, 0, 0, 0, 0, 0};
  #pragma unroll 4
  for (int c = 0; c < 512; c++) {
    double f = (double)fbase[(size_t)c * 2500];
    #pragma unroll
    for (int jj = 0; jj < 8; jj++) acc[jj] += f * (double)wsh[jj * 512 + c];
  }
  if (!pv) return;
  #pragma unroll
  for (int jj = 0; jj < 8; jj++) {
    int oc = ocg * 8 + jj;
    if (oc >= 54) break;
    double v = acc[jj] + bias[jj];
    if (oc < 36) {
      locD[(size_t)n * 90000 + (size_t)p * 36 + oc] = v;
      out[(size_t)n * 90000 + (size_t)p * 36 + oc] = (float)v;
    } else {
      scoreD[(size_t)n * 45000 + (size_t)p * 18 + (oc - 36)] = v;
      out[360000 + (size_t)n * 45000 + (size_t)p * 18 + (oc - 36)] = (float)v;
    }
  }
}

// robust scalar decode: harness may deliver python ints as int32 or float32
__device__ inline double decode_dim(const int* p) {
  int v = p[0];
  if (v > 0 && v < 1000000) return (double)v;
  return (double)__int_as_float(v);
}

// ======== zero hist/hist2/sValid/sBoxD — MUST run after heads (aliases) ======
__global__ void zero_kernel(unsigned* __restrict__ hist, unsigned* __restrict__ hist2,
                            int* __restrict__ sValid, double* __restrict__ sBoxD)
{
  const int i = blockIdx.x * 256 + threadIdx.x;
  if (i < 262144) { hist[i] = 0u; hist2[i] = 0u; }
  if (i < 12000) sValid[i] = 0;
  if (i < 48000) sBoxD[i] = 0.0;
}

// ======================= anchors + loc2bbox + clip + valid + fg (f64) ========
// R26: histogram atomics wave-aggregated (scores cluster -> same-bin
// contention). One atomicAdd(+popcount) per distinct key per wave.
__global__ void prep_kernel(const double* __restrict__ locD,
                            const double* __restrict__ scoreD,
                            const int* __restrict__ img_h_p, const int* __restrict__ img_w_p,
                            double* __restrict__ roiD, double* __restrict__ selD,
                            unsigned* __restrict__ hist, float* __restrict__ d_out)
{
  const int i = blockIdx.x * 256 + threadIdx.x;
  const int n = blockIdx.y;
  if (i >= 22500) return;
  const int p = i / 9, ab = i - p * 9;
  const int y = p / 50, x = p - y * 50;
  const int ri = ab / 3, sidx = ab - ri * 3;
  const double rr = (ri == 0) ? 0.5 : (ri == 1 ? 1.0 : 2.0);
  const double sc = (sidx == 0) ? 8.0 : (sidx == 1 ? 16.0 : 32.0);
  const double hh = 16.0 * sc * sqrt(rr);
  const double wd = 16.0 * sc * sqrt(1.0 / rr);
  const float bx1 = (float)(8.0 - wd * 0.5), by1 = (float)(8.0 - hh * 0.5);
  const float bx2 = (float)(8.0 + wd * 0.5), by2 = (float)(8.0 + hh * 0.5);
  const float sxf = (float)(x * 16), syf = (float)(y * 16);
  const float ax1 = bx1 + sxf, ay1 = by1 + syf, ax2 = bx2 + sxf, ay2 = by2 + syf;
  if (n == 0) {
    ((float4*)(d_out + 546000))[i] = make_float4(ax1, ay1, ax2, ay2);
  }
  const double l0 = locD[(size_t)n * 90000 + (size_t)i * 4 + 0];
  const double l1 = locD[(size_t)n * 90000 + (size_t)i * 4 + 1];
  const double l2 = locD[(size_t)n * 90000 + (size_t)i * 4 + 2];
  const double l3 = locD[(size_t)n * 90000 + (size_t)i * 4 + 3];
  const double s0 = scoreD[(size_t)n * 45000 + (size_t)i * 2 + 0];
  const double s1 = scoreD[(size_t)n * 45000 + (size_t)i * 2 + 1];
  const double aw = (double)ax2 - (double)ax1, ah = (double)ay2 - (double)ay1;
  const double acx = (double)ax1 + 0.5 * aw, acy = (double)ay1 + 0.5 * ah;
  const double cx = l0 * aw + acx, cy = l1 * ah + acy;
  const double ww = exp(l2) * aw, hh2 = exp(l3) * ah;
  double x1 = cx - 0.5 * ww, y1 = cy - 0.5 * hh2;
  double x2 = cx + 0.5 * ww, y2 = cy + 0.5 * hh2;
  const double fw = decode_dim(img_w_p), fh = decode_dim(img_h_p);
  x1 = fmin(fmax(x1, 0.0), fw); x2 = fmin(fmax(x2, 0.0), fw);
  y1 = fmin(fmax(y1, 0.0), fh); y2 = fmin(fmax(y2, 0.0), fh);
  const bool valid = (x2 - x1 + 1.0 >= 16.0) && (y2 - y1 + 1.0 >= 16.0);
  const double m = fmax(s0, s1);
  const double e0 = exp(s0 - m), e1 = exp(s1 - m);
  const double fg = e1 / (e0 + e1);
  double* rb = roiD + ((size_t)n * 22500 + i) * 4;
  rb[0] = x1; rb[1] = y1; rb[2] = x2; rb[3] = y2;
  selD[(size_t)n * 22500 + i] = valid ? fg : -INFINITY;
  // fg in (0,1): positive f64 -> bits order == value order
  const unsigned key = (unsigned)((unsigned long long)__double_as_longlong(fg) >> 48);
  const int lane = threadIdx.x & 63;
  unsigned long long act = __ballot(valid);
  while (act) {
    const int leader = __ffsll(act) - 1;
    const unsigned k0 = (unsigned)__shfl((int)key, leader);
    const unsigned long long same = __ballot(valid && key == k0);
    if (lane == leader)
      atomicAdd(&hist[n * 65536 + k0], (unsigned)__popcll(same));
    act &= ~same;
  }
}

// ======================= threshold L1: largest key covering top-3000 ========
// R28: back to R26 form — per-thread contiguous sums (cache-line reuse,
// independent pipelined loads). R27's shfl-reduce serialized the chain.
__global__ __launch_bounds__(256) void thresh_kernel(
    const unsigned* __restrict__ hist, unsigned* __restrict__ thrP,
    unsigned* __restrict__ cntAbove)
{
  const int n = blockIdx.x;
  const int t = threadIdx.x;
  __shared__ unsigned csum[256];
  __shared__ unsigned hv[256];
  __shared__ int cstar;
  __shared__ unsigned sufS;
  const unsigned* h = hist + (size_t)n * 65536;
  unsigned s = 0;
  for (int k = 0; k < 256; k++) s += h[t * 256 + k];
  csum[t] = s;
  __syncthreads();
  if (t == 0) {
    unsigned suf = 0; int cs = -1;
    for (int c = 255; c >= 0; c--) {
      if (suf + csum[c] >= 3000u) { cs = c; break; }
      suf += csum[c];
    }
    cstar = cs; sufS = suf;
  }
  __syncthreads();
  const int cs = cstar;
  if (cs >= 0) hv[t] = h[cs * 256 + t];
  __syncthreads();
  if (t == 0) {
    unsigned Tkey = 0, above = 0;
    if (cs >= 0) {
      unsigned suf = sufS;
      for (int v = 255; v >= 0; v--) {
        if (suf + hv[v] >= 3000u) { Tkey = (unsigned)(cs * 256 + v); above = suf; break; }
        suf += hv[v];
      }
    }
    thrP[n] = Tkey;        // 0 if <3000 valid -> all valid become candidates
    cntAbove[n] = above;   // strictly < 3000 by construction
  }
}

// ============ L2 refinement: histogram bits 47:32 within threshold class ====
__global__ void hist2_kernel(const double* __restrict__ selD,
                             const unsigned* __restrict__ thrP,
                             unsigned* __restrict__ hist2)
{
  const int i = blockIdx.x * 256 + threadIdx.x;
  const int n = blockIdx.y;
  if (i >= 22500) return;
  double s = selD[(size_t)n * 22500 + i];
  if (!(s > -INFINITY)) return;
  unsigned long long b = (unsigned long long)__double_as_longlong(s);
  if ((unsigned)(b >> 48) == thrP[n]) {
    unsigned key2 = (unsigned)(b >> 32) & 0xFFFFu;
    atomicAdd(&hist2[n * 65536 + key2], 1u);   // keys well-spread: low contention
  }
}

// thresh2: largest key2 s.t. cntAbove + suffix2 >= 3000 (0 if class empty)
// R28: back to R26 form (see thresh note).
__global__ __launch_bounds__(256) void thresh2_kernel(
    const unsigned* __restrict__ hist2, const unsigned* __restrict__ cntAbove,
    unsigned* __restrict__ thr2P)
{
  const int n = blockIdx.x;
  const int t = threadIdx.x;
  __shared__ unsigned csum[256];
  __shared__ unsigned hv[256];
  __shared__ int cstar;
  __shared__ unsigned sufS;
  const unsigned* h = hist2 + (size_t)n * 65536;
  const unsigned target = 3000u - cntAbove[n];   // >= 1
  unsigned s = 0;
  for (int k = 0; k < 256; k++) s += h[t * 256 + k];
  csum[t] = s;
  __syncthreads();
  if (t == 0) {
    unsigned suf = 0; int cs = -1;
    for (int c = 255; c >= 0; c--) {
      if (suf + csum[c] >= target) { cs = c; break; }
      suf += csum[c];
    }
    cstar = cs; sufS = suf;
  }
  __syncthreads();
  const int cs = cstar;
  if (cs >= 0) hv[t] = h[cs * 256 + t];
  __syncthreads();
  if (t == 0) {
    unsigned T2 = 0;
    if (cs >= 0) {
      unsigned suf = sufS;
      for (int v = 255; v >= 0; v--) {
        suf += hv[v];
        if (suf >= target) { T2 = (unsigned)(cs * 256 + v); break; }
      }
    }
    thr2P[n] = T2;   // 0 if class can't reach target (e.g. <3000 valid total)
  }
}

// ============ deterministic 2-phase compaction (no atomics) =================
__device__ inline bool cand_flag(const double* __restrict__ selD,
                                 const unsigned* __restrict__ thrP,
                                 const unsigned* __restrict__ thr2P,
                                 int n, int i, double* sOut) {
  double s = selD[(size_t)n * 22500 + i];
  *sOut = s;
  if (!(s > -INFINITY)) return false;
  unsigned long long b = (unsigned long long)__double_as_longlong(s);
  unsigned key = (unsigned)(b >> 48);
  unsigned T = thrP[n];
  if (key != T) return key > T;
  return ((unsigned)(b >> 32) & 0xFFFFu) >= thr2P[n];
}

// phase 1: per-block candidate counts
__global__ __launch_bounds__(256) void ccount_kernel(
    const double* __restrict__ selD, const unsigned* __restrict__ thrP,
    const unsigned* __restrict__ thr2P, unsigned* __restrict__ blkCnt)
{
  const int i = blockIdx.x * 256 + threadIdx.x;
  const int n = blockIdx.y;
  double s;
  bool f = (i < 22500) && cand_flag(selD, thrP, thr2P, n, i, &s);
  unsigned long long b = __ballot(f);
  __shared__ unsigned wc[4];
  const int wv = threadIdx.x >> 6, lane = threadIdx.x & 63;
  if (lane == 0) wc[wv] = (unsigned)__popcll(b);
  __syncthreads();
  if (threadIdx.x == 0)
    blkCnt[n * 88 + blockIdx.x] = wc[0] + wc[1] + wc[2] + wc[3];
}

// phase 2 (R27, kept): one wave per n; shfl_up exclusive prefix over 88
// entries (64 + 24). Exact integer prefix -> blkOff/mOut bit-identical.
__global__ __launch_bounds__(256) void cscan_kernel(
    const unsigned* __restrict__ blkCnt, unsigned* __restrict__ blkOff,
    unsigned* __restrict__ mOut)
{
  const int n = threadIdx.x >> 6;
  const int lane = threadIdx.x & 63;
  const int e0 = (int)blkCnt[n * 88 + lane];
  const int e1 = (lane < 24) ? (int)blkCnt[n * 88 + 64 + lane] : 0;
  int s0 = e0;
  #pragma unroll
  for (int off = 1; off < 64; off <<= 1) {
    int t2 = __shfl_up(s0, off);
    if (lane >= off) s0 += t2;
  }
  const int tot0 = __shfl(s0, 63);
  int s1 = e1;
  #pragma unroll
  for (int off = 1; off < 64; off <<= 1) {
    int t2 = __shfl_up(s1, off);
    if (lane >= off) s1 += t2;
  }
  const int tot1 = __shfl(s1, 63);
  blkOff[n * 88 + lane] = (unsigned)(s0 - e0);
  if (lane < 24) blkOff[n * 88 + 64 + lane] = (unsigned)(tot0 + s1 - e1);
  if (lane == 0) mOut[n] = (unsigned)(tot0 + tot1);
}

// phase 3: index-ordered scatter at deterministic offsets
__global__ __launch_bounds__(256) void cscatter_kernel(
    const double* __restrict__ selD, const unsigned* __restrict__ thrP,
    const unsigned* __restrict__ thr2P, const unsigned* __restrict__ blkOff,
    int* __restrict__ candIdx, double* __restrict__ candS)
{
  const int i = blockIdx.x * 256 + threadIdx.x;
  const int n = blockIdx.y;
  double s = 0.0;
  bool f = (i < 22500) && cand_flag(selD, thrP, thr2P, n, i, &s);
  unsigned long long b = __ballot(f);
  const int wv = threadIdx.x >> 6, lane = threadIdx.x & 63;
  __shared__ unsigned wc[4];
  if (lane == 0) wc[wv] = (unsigned)__popcll(b);
  __syncthreads();
  unsigned woff = 0;
  for (int w = 0; w < wv; w++) woff += wc[w];
  unsigned lpre = (unsigned)__popcll(b & ((1ull << lane) - 1ull));
  if (f) {
    unsigned pos = blkOff[n * 88 + blockIdx.x] + woff + lpre;
    candIdx[(size_t)n * 22500 + pos] = i;
    candS[(size_t)n * 22500 + pos] = s;
  }
}

// ============ exact rank among candidates, j-axis split 12 ways =============
#define RCHUNKS 12
#define RSTRIDE 22528

__global__ __launch_bounds__(256) void crank1_kernel(
    const unsigned* __restrict__ mOut, const int* __restrict__ candIdx,
    const double* __restrict__ candS, int* __restrict__ partialR)
{
  const int n = blockIdx.z;
  const int m = (int)mOut[n];
  if ((int)(blockIdx.x * 256) >= m) return;   // block-uniform early exit
  const int c = blockIdx.y;
  const int tid = blockIdx.x * 256 + threadIdx.x;
  const bool act = (tid < m);
  const double si = act ? candS[(size_t)n * 22500 + tid] : 0.0;
  const int ii = act ? candIdx[(size_t)n * 22500 + tid] : 0x7fffffff;
  const int jlo = (int)(((long long)c * m) / RCHUNKS);
  const int jhi = (int)(((long long)(c + 1) * m) / RCHUNKS);
  __shared__ double sv[256];
  __shared__ int siv[256];
  int rank = 0;
  for (int j0 = jlo; j0 < jhi; j0 += 256) {
    __syncthreads();
    const int jl = j0 + threadIdx.x;
    if (jl < jhi) {
      sv[threadIdx.x] = candS[(size_t)n * 22500 + jl];
      siv[threadIdx.x] = candIdx[(size_t)n * 22500 + jl];
    }
    __syncthreads();
    const int lim = (jhi - j0 < 256) ? (jhi - j0) : 256;
    #pragma unroll 8
    for (int k = 0; k < lim; k++) {
      const double sj = sv[k];
      const int ij = siv[k];
      rank += ((sj > si) || (sj == si && ij < ii)) ? 1 : 0;
    }
  }
  if (act) partialR[((size_t)n * RCHUNKS + c) * RSTRIDE + tid] = rank;
}

__global__ __launch_bounds__(256) void crank2_kernel(
    const unsigned* __restrict__ mOut, const int* __restrict__ candIdx,
    const int* __restrict__ partialR, const double* __restrict__ roiD,
    double* __restrict__ sBoxD, int* __restrict__ sValid)
{
  const int n = blockIdx.y;
  const int m = (int)mOut[n];
  const int tid = blockIdx.x * 256 + threadIdx.x;
  if (tid >= m) return;
  int rank = 0;
  #pragma unroll
  for (int c = 0; c < RCHUNKS; c++)
    rank += partialR[((size_t)n * RCHUNKS + c) * RSTRIDE + tid];
  if (rank < 3000) {
    const int ii = candIdx[(size_t)n * 22500 + tid];
    const double* rb = roiD + ((size_t)n * 22500 + ii) * 4;
    double* db = sBoxD + ((size_t)n * 3000 + rank) * 4;
    db[0] = rb[0]; db[1] = rb[1]; db[2] = rb[2]; db[3] = rb[3];
    sValid[n * 3000 + rank] = 1;
  }
}

// ======================= NMS phase A: suppression bitmask (f64 IoU) ==========
// sup layout WORD-MAJOR (R25): sup[((n*47 + wj)*3008) + i]; coalesced stores.
__global__ void supmat_kernel(const double* __restrict__ sBoxD,
                              unsigned long long* __restrict__ sup)
{
  const int wj = blockIdx.x, ig = blockIdx.y, n = blockIdx.z;
  const int lane = threadIdx.x;
  const int i = ig * 64 + lane;
  unsigned long long* dst = sup + ((size_t)n * 47 + wj) * 3008;
  if (wj < ig) {                       // strictly below diagonal: all zero
    if (i < 3000) dst[i] = 0ull;
    return;
  }
  __shared__ double jb[64][4];
  const int j0 = wj * 64;
  {
    int j = j0 + lane;
    if (j < 3000) {
      const double* b = sBoxD + ((size_t)n * 3000 + j) * 4;
      jb[lane][0] = b[0]; jb[lane][1] = b[1]; jb[lane][2] = b[2]; jb[lane][3] = b[3];
    } else {
      jb[lane][0] = 0; jb[lane][1] = 0; jb[lane][2] = 0; jb[lane][3] = 0;
    }
  }
  __syncthreads();
  if (i >= 3000) return;
  const double* bi = sBoxD + ((size_t)n * 3000 + i) * 4;
  const double bx1 = bi[0], by1 = bi[1], bx2 = bi[2], by2 = bi[3];
  const double ai = (bx2 - bx1) * (by2 - by1);
  unsigned long long msk = 0;
  #pragma unroll 2
  for (int tt = 0; tt < 64; tt++) {
    const int j = j0 + tt;
    const double jx1 = jb[tt][0], jy1 = jb[tt][1], jx2 = jb[tt][2], jy2 = jb[tt][3];
    double iw = fmax(fmin(bx2, jx2) - fmax(bx1, jx1), 0.0);
    double ih = fmax(fmin(by2, jy2) - fmax(by1, jy1), 0.0);
    double inter = iw * ih;
    double aj = (jx2 - jx1) * (jy2 - jy1);
    double iou = inter / (ai + aj - inter + 1e-9);
    if (iou > 0.7 && j > i && j < 3000) msk |= (1ull << tt);
  }
  dst[i] = msk;
}

// ======================= NMS phase B: alive-only scan, early stop at 300 =====
// R26: serial kept-loop touches ONLY LDS + shfl; box emission deferred.
__global__ __launch_bounds__(64) void nms_scan_kernel(
    const double* __restrict__ sBoxD,
    const int* __restrict__ sValid,
    const unsigned long long* __restrict__ sup,
    float* __restrict__ out)
{
  const int n = blockIdx.x;
  const int lane = threadIdx.x;
  unsigned long long alive = 0;
  for (int w = 0; w < 47; w++) {
    int idx = w * 64 + lane;
    int v = (idx < 3000) ? sValid[(size_t)n * 3000 + idx] : 0;
    unsigned long long bm = __ballot(v != 0);
    if (lane == w) alive = bm;
  }
  const unsigned long long* sbase = sup + (size_t)n * 47 * 3008;

  __shared__ unsigned long long rows[2][64][49];
  __shared__ int keptIdx[304];
  unsigned long long stg[47];

  auto STAGE_LOAD = [&](int w) {
    const unsigned long long* src = sbase + w * 64 + lane;
    #pragma unroll
    for (int k = 0; k < 47; k++) stg[k] = src[(size_t)k * 3008];
  };
  auto STAGE_WRITE = [&](int buf) {
    #pragma unroll
    for (int k = 0; k < 47; k++) rows[buf][lane][k] = stg[k];
  };

  STAGE_LOAD(0);
  STAGE_WRITE(0);
  __syncthreads();
  STAGE_LOAD(1);

  int kept = 0;
  for (int w = 0; w < 47 && kept < 300; w++) {
    const int buf = w & 1;
    unsigned long long t = __shfl(alive, w);
    while (t != 0ull && kept < 300) {
      const int b = __ffsll(t) - 1;
      const int i = w * 64 + b;
      unsigned long long row = (lane < 47) ? rows[buf][b][lane] : 0ull;
      alive &= ~row;
      if (lane == 0) keptIdx[kept] = i;    // ds_write: off the serial chain
      kept++;
      const unsigned long long hi = (b == 63) ? 0ull : (~0ull << (b + 1));
      t = __shfl(alive, w) & hi;
    }
    if (w + 1 < 47) {
      STAGE_WRITE(buf ^ 1);
      __syncthreads();
      if (w + 2 < 47) STAGE_LOAD(w + 2);
    }
  }
  __syncthreads();                         // keptIdx visible to all lanes

  float4* rois4 = (float4*)(out + 540000);
  for (int r = lane; r < kept; r += 64) {
    const int i = keptIdx[r];
    const double* bb = sBoxD + ((size_t)n * 3000 + i) * 4;
    rois4[n * 300 + r] = make_float4((float)bb[0], (float)bb[1],
                                     (float)bb[2], (float)bb[3]);
  }
  for (int k = kept + lane; k < 300; k += 64)
    rois4[n * 300 + k] = make_float4(0, 0, 0, 0);
  for (int k = lane; k < 300; k += 64)
    out[544800 + n * 300 + k] = (float)n;
}

// ======================= launch =======================
extern "C" void kernel_launch(void* const* d_in, const int* in_sizes, int n_in,
                              void* d_out, int out_size, void* d_ws, size_t ws_size,
                              hipStream_t stream) {
  const float* x        = (const float*)d_in[0];
  const float* conv1_w  = (const float*)d_in[1];
  const float* conv1_b  = (const float*)d_in[2];
  const float* loc_w    = (const float*)d_in[3];
  const float* loc_b    = (const float*)d_in[4];
  const float* score_w  = (const float*)d_in[5];
  const float* score_b  = (const float*)d_in[6];
  const int*   img_h    = (const int*)d_in[7];
  const int*   img_w    = (const int*)d_in[8];
  float* out = (float*)d_out;
  char* ws = (char*)d_ws;

  float*    featF = (float*)(ws);                       // [0, 20,480,000)
  _Float16* Whi   = (_Float16*)(ws + 20480000);         // +4,718,592
  _Float16* Wlo   = (_Float16*)(ws + 25198592);         // +4,718,592
  float*    Xt    = (float*)(ws + 29917184);            // +10,240,000 -> 40,157,184
  double*   locD   = (double*)(ws + 20480000);          // +2,880,000 (over Whi, dead)
  double*   scoreD = (double*)(ws + 23360000);          // +1,440,000 -> 24,800,000
  double* roiD   = (double*)(ws);                  // [0, 2,880,000)
  double* selD   = (double*)(ws + 2880000);        // +720,000
  double* sBoxD  = (double*)(ws + 3600000);        // +384,000
  int*    sValid = (int*)(ws + 4000000);           // +48,000
  unsigned long long* sup = (unsigned long long*)(ws + 4100000);  // +4,524,032 (word-major) -> 8,624,032
  unsigned* hist   = (unsigned*)(ws + 8700000);    // +1,048,576
  unsigned* blkCnt = (unsigned*)(ws + 9750000);    // +1,408
  unsigned* blkOff = (unsigned*)(ws + 9752000);    // +1,408
  unsigned* mOut   = (unsigned*)(ws + 9754000);    // +16
  unsigned* thrP   = (unsigned*)(ws + 9755000);    // +16
  unsigned* cntAb  = (unsigned*)(ws + 9756000);    // +16
  unsigned* thr2P  = (unsigned*)(ws + 9757000);    // +16
  int*      candIdx= (int*)(ws + 9760000);         // +360,000
  double*   candS  = (double*)(ws + 10200000);     // +720,000 -> 10,920,000
  unsigned* hist2  = (unsigned*)(ws + 10920000);   // +1,048,576 -> 11,968,576
  int*      partialR = (int*)(ws + 12000000);      // +4,325,376 -> 16,325,376

  wsplit_kernel<<<512, 256, 0, stream>>>(conv1_w, Whi, Wlo);
  xt_kernel<<<dim3(50, 4), 256, 0, stream>>>(x, Xt);
  conv_f16_kernel<<<dim3(50, 2, 4), 256, 0, stream>>>(Xt, Whi, Wlo, conv1_b, featF);
  heads_kernel<<<dim3(10, 7, 4), 256, 0, stream>>>(featF, loc_w, loc_b, score_w, score_b,
                                                   locD, scoreD, out);
  zero_kernel<<<1024, 256, 0, stream>>>(hist, hist2, sValid, sBoxD);  // after heads!
  prep_kernel<<<dim3(88, 4), 256, 0, stream>>>(locD, scoreD, img_h, img_w,
                                               roiD, selD, hist, out);
  thresh_kernel<<<4, 256, 0, stream>>>(hist, thrP, cntAb);
  hist2_kernel<<<dim3(88, 4), 256, 0, stream>>>(selD, thrP, hist2);
  thresh2_kernel<<<4, 256, 0, stream>>>(hist2, cntAb, thr2P);
  ccount_kernel<<<dim3(88, 4), 256, 0, stream>>>(selD, thrP, thr2P, blkCnt);
  cscan_kernel<<<1, 256, 0, stream>>>(blkCnt, blkOff, mOut);
  cscatter_kernel<<<dim3(88, 4), 256, 0, stream>>>(selD, thrP, thr2P, blkOff, candIdx, candS);
  crank1_kernel<<<dim3(88, RCHUNKS, 4), 256, 0, stream>>>(mOut, candIdx, candS, partialR);
  crank2_kernel<<<dim3(88, 4), 256, 0, stream>>>(mOut, candIdx, partialR, roiD, sBoxD, sValid);
  supmat_kernel<<<dim3(47, 47, 4), 64, 0, stream>>>(sBoxD, sup);
  nms_scan_kernel<<<4, 64, 0, stream>>>(sBoxD, sValid, sup, out);
}

// Round 13
// 607.857 us; speedup vs baseline: 1.0708x; 1.0104x over previous
//
#include <hip/hip_runtime.h>
#include <math.h>

// ---------------- problem constants ----------------
// x: (4,512,50,50) f32; conv1_w: (512,512,3,3); heads: 36 loc + 18 score ch
// outputs (f32, concat): rpn_locs 360000 | rpn_scores 180000 @360000 |
//   rois 4800 @540000 | roi_indices 1200 @544800 | anchor 90000 @546000
//
// R17: conv3x3 f16-split MFMA. 1423us. R18: 2-level radix. 1199us.
// R19: alive-only NMS. 994us. R20: crank split. 744us.
// R21 FAILED perf (reg-cap spill). R22: revert. 749us.
// R23 FAILED correctness (conv ULPs -> selection flip). conv/heads/prep
//   arithmetic FROZEN; only bitwise-identity-preserving changes allowed.
// R24: revert. 749.5us. R25: sup word-major: -3us.
// R26: nms deferred emission + prep wave-aggregated atomics. 613us.
// R27 REGRESSED (651us): thresh shfl-reduce serialized the chain.
// R28: revert thresh; keep parallel cscan. 614us.
// R29: launch-count cuts, all integer-exact:
//  (a) wsplit+xt fused (block-partitioned, shared LDS) -> -1 launch.
//  (b) cscan eliminated: mOut via integer atomicAdd in ccount
//      (order-independent -> deterministic); cscatter computes its own
//      block-prefix from L2-resident blkCnt (masked loads + shfl_xor
//      reduce). Exact integer prefix -> positions bit-identical.
//  (c) sup pre-zeroed in zero_kernel (dead-featF alias); supmat
//      below-diagonal blocks return WITHOUT storing.
// Pre-commitment: if gain < 10us, declare practical plateau.

typedef _Float16 f16x8 __attribute__((ext_vector_type(8)));
typedef float f32x4 __attribute__((ext_vector_type(4)));

// ============ fused W pre-split (blocks 0..511) + X transpose (512..711) ====
__global__ __launch_bounds__(256) void prepin_kernel(
    const float* __restrict__ wg, _Float16* __restrict__ whi,
    _Float16* __restrict__ wlo, const float* __restrict__ xg,
    float* __restrict__ xt)
{
  __shared__ float sh[6656];   // wsplit uses 4608; xt uses 128*52=6656
  if (blockIdx.x < 512) {
    const int oc = blockIdx.x;
    float* wb = sh;
    for (int e = threadIdx.x; e < 4608; e += 256) wb[e] = wg[(size_t)oc * 4608 + e];
    __syncthreads();
    const int ochi = oc >> 4, m = oc & 15;
    for (int e = threadIdx.x; e < 4608; e += 256) {
      int tap = e / 512, ic = e & 511;
      float v = wb[ic * 9 + tap] * 256.f;   // exact scale 2^8
      _Float16 h = (_Float16)v;             // RNE
      float r = v - (float)h;               // exact residual
      _Float16 l = (_Float16)r;
      int icg = ic >> 3, icl = ic & 7;
      size_t idx = ((((size_t)ochi * 9 + tap) * 64 + icg) * 16 + m) * 8 + icl;
      whi[idx] = h;
      wlo[idx] = l;
    }
  } else {
    const int idx0 = blockIdx.x - 512;     // 0..199
    const int y = idx0 % 50, n = idx0 / 50;
    float (*tb)[52] = (float(*)[52])sh;
    for (int icc = 0; icc < 4; icc++) {
      __syncthreads();
      for (int e = threadIdx.x; e < 128 * 50; e += 256) {
        int icL = e / 50, xx = e - icL * 50;
        tb[icL][xx] = 16.f * xg[(((size_t)n * 512 + icc * 128 + icL) * 50 + y) * 50 + xx];
      }
      __syncthreads();
      for (int e = threadIdx.x; e < 50 * 128; e += 256) {
        int xx = e >> 7, icL = e & 127;
        xt[(((size_t)n * 50 + y) * 50 + xx) * 512 + icc * 128 + icL] = tb[icL][xx];
      }
    }
  }
}

// ======================= conv 3x3 via f16-split MFMA (FROZEN) ==============
#define XSLOTS 66
#define PADIC  40

__global__ __launch_bounds__(256, 2) void conv_f16_kernel(
    const float* __restrict__ xt, const _Float16* __restrict__ whi,
    const _Float16* __restrict__ wlo, const float* __restrict__ bg,
    float* __restrict__ featF)
{
  const int y0 = blockIdx.x, ocb = blockIdx.y, n = blockIdx.z;
  const int t = threadIdx.x;
  const int lane = t & 63, wv = t >> 6;
  const int c16 = lane & 15, g = lane >> 4;

  __shared__ _Float16 sX[2][2][3][XSLOTS][PADIC];  // [buf][split][row][xslot][ic]

  for (int e = t; e < (int)(sizeof(sX) / 4); e += 256) ((float*)sX)[e] = 0.f;

  int gbase[3], grw[3], gxs[3], gig[3];
  bool gok[3];
  #pragma unroll
  for (int k = 0; k < 3; k++) {
    int gg = t + k * 256;
    bool ok = gg < 624;
    int row = ok ? gg / 208 : 0;
    int rem = ok ? gg - row * 208 : 0;
    int xs = rem >> 2, ig = rem & 3;
    int yy = y0 + row - 1, xc = xs - 1;
    bool val = ok && yy >= 0 && yy < 50 && xc >= 0 && xc < 50;
    grw[k] = row; gxs[k] = xs; gig[k] = ig; gok[k] = ok;
    gbase[k] = val ? ((((n * 50 + yy) * 50 + xc) << 9) + ig * 8) : -1;
  }

  float4 xr[3][2];
  auto LOADX = [&](int cc) {
    const int ic0 = cc * 32;
    #pragma unroll
    for (int k = 0; k < 3; k++) {
      if (gbase[k] >= 0) {
        const float4* p = (const float4*)(xt + gbase[k] + ic0);
        xr[k][0] = p[0];
        xr[k][1] = p[1];
      } else {
        xr[k][0] = make_float4(0.f, 0.f, 0.f, 0.f);
        xr[k][1] = make_float4(0.f, 0.f, 0.f, 0.f);
      }
    }
  };
  auto WRITEX = [&](int buf) {
    #pragma unroll
    for (int k = 0; k < 3; k++) {
      if (!gok[k]) continue;
      float v[8] = {xr[k][0].x, xr[k][0].y, xr[k][0].z, xr[k][0].w,
                    xr[k][1].x, xr[k][1].y, xr[k][1].z, xr[k][1].w};
      f16x8 h8, l8;
      #pragma unroll
      for (int j = 0; j < 8; j++) {
        _Float16 h = (_Float16)v[j];   // RNE
        float r = v[j] - (float)h;     // exact
        h8[j] = h;
        l8[j] = (_Float16)r;
      }
      *(f16x8*)&sX[buf][0][grw[k]][gxs[k]][gig[k] * 8] = h8;
      *(f16x8*)&sX[buf][1][grw[k]][gxs[k]][gig[k] * 8] = l8;
    }
  };

  f16x8 Ah[2][4], Al[2][4];
  const int ochiB = ocb * 16 + wv * 4;
  auto LOADA = [&](int par, int tap, int cc) {
    #pragma unroll
    for (int os = 0; os < 4; os++) {
      size_t idx = ((((size_t)(ochiB + os) * 9 + tap) * 64 + cc * 4 + g) * 16 + c16) * 8;
      Ah[par][os] = *(const f16x8*)(whi + idx);
      Al[par][os] = *(const f16x8*)(wlo + idx);
    }
  };

  __syncthreads();          // zero-fill visible before staging
  LOADX(0);
  WRITEX(0);
  LOADA(0, 0, 0);

  f32x4 acc[4][4];
  #pragma unroll
  for (int os = 0; os < 4; os++)
    #pragma unroll
    for (int nt = 0; nt < 4; nt++) acc[os][nt] = (f32x4){0.f, 0.f, 0.f, 0.f};

  __syncthreads();

  for (int cc = 0; cc < 16; cc++) {
    const int buf = cc & 1;
    if (cc < 15) LOADX(cc + 1);          // issue global loads early (T14)
    #pragma unroll
    for (int tap = 0; tap < 9; tap++) {
      const int cur = tap & 1;
      if (tap < 8) LOADA(cur ^ 1, tap + 1, cc);
      else if (cc < 15) LOADA(1, 0, cc + 1);
      const int ky = tap / 3, kx = tap - ky * 3;
      #pragma unroll
      for (int nt = 0; nt < 4; nt++) {
        const int xsl = nt * 16 + c16 + kx;   // x = px + kx - 1, slot = x+1
        f16x8 bh = *(const f16x8*)&sX[buf][0][ky][xsl][g * 8];
        f16x8 bl = *(const f16x8*)&sX[buf][1][ky][xsl][g * 8];
        #pragma unroll
        for (int os = 0; os < 4; os++) {
          acc[os][nt] = __builtin_amdgcn_mfma_f32_16x16x32_f16(Ah[cur][os], bh, acc[os][nt], 0, 0, 0);
          acc[os][nt] = __builtin_amdgcn_mfma_f32_16x16x32_f16(Ah[cur][os], bl, acc[os][nt], 0, 0, 0);
          acc[os][nt] = __builtin_amdgcn_mfma_f32_16x16x32_f16(Al[cur][os], bh, acc[os][nt], 0, 0, 0);
        }
      }
      if (tap == 8) {  // restore parity: next chunk's tap0 sits in slot 1
        #pragma unroll
        for (int os = 0; os < 4; os++) { Ah[0][os] = Ah[1][os]; Al[0][os] = Al[1][os]; }
      }
    }
    if (cc < 15) WRITEX(buf ^ 1);
    __syncthreads();
  }

  // epilogue: descale 2^-12 (W x256 * X x16), bias, relu.
  const int ocwbase = ocb * 256 + wv * 64;
  #pragma unroll
  for (int nt = 0; nt < 4; nt++) {
    const int px = nt * 16 + c16;
    if (px < 50) {
      #pragma unroll
      for (int os = 0; os < 4; os++) {
        #pragma unroll
        for (int i = 0; i < 4; i++) {
          const int oc = ocwbase + os * 16 + g * 4 + i;
          featF[(((size_t)n * 512 + oc) * 50 + y0) * 50 + px] =
              fmaxf(acc[os][nt][i] * (1.f / 4096.f) + bg[oc], 0.f);
        }
      }
    }
  }
}

// ======================= 1x1 heads (loc 36 + score 18), f64, DETERMINISTIC ===
__global__ __launch_bounds__(256) void heads_kernel(
    const float* __restrict__ featF,
    const float* __restrict__ loc_w, const float* __restrict__ loc_b,
    const float* __restrict__ score_w, const float* __restrict__ score_b,
    double* __restrict__ locD, double* __restrict__ scoreD,
    float* __restrict__ out)
{
  const int p = blockIdx.x * 256 + threadIdx.x;
  const int ocg = blockIdx.y;
  const int n = blockIdx.z;
  const bool pv = (p < 2500);
  const int pp = pv ? p : 0;
  const float* fbase = featF + (size_t)n * 512 * 2500 + pp;

  __shared__ float wsh[8 * 512];
  double bias[8];
  #pragma unroll
  for (int jj = 0; jj < 8; jj++) {
    int oc = ocg * 8 + jj;
    int occ = (oc < 54) ? oc : 0;
    bias[jj] = (occ < 36) ? (double)loc_b[occ] : (double)score_b[occ - 36];
  }
  for (int e = threadIdx.x; e < 8 * 512; e += 256) {
    int jj = e >> 9, c = e & 511;
    int oc = ocg * 8 + jj;
    int occ = (oc < 54) ? oc : 0;
    wsh[e] = (occ < 36) ? loc_w[(size_t)occ * 512 + c]
                        : score_w[(size_t)(occ - 36) * 512 + c];
  }
  __syncthreads();

  double acc[8] = {0, 0, 0, 0, 0, 0, 0, 0};
  #pragma unroll 4
  for (int c = 0; c < 512; c++) {
    double f = (double)fbase[(size_t)c * 2500];
    #pragma unroll
    for (int jj = 0; jj < 8; jj++) acc[jj] += f * (double)wsh[jj * 512 + c];
  }
  if (!pv) return;
  #pragma unroll
  for (int jj = 0; jj < 8; jj++) {
    int oc = ocg * 8 + jj;
    if (oc >= 54) break;
    double v = acc[jj] + bias[jj];
    if (oc < 36) {
      locD[(size_t)n * 90000 + (size_t)p * 36 + oc] = v;
      out[(size_t)n * 90000 + (size_t)p * 36 + oc] = (float)v;
    } else {
      scoreD[(size_t)n * 45000 + (size_t)p * 18 + (oc - 36)] = v;
      out[360000 + (size_t)n * 45000 + (size_t)p * 18 + (oc - 36)] = (float)v;
    }
  }
}

// robust scalar decode: harness may deliver python ints as int32 or float32
__device__ inline double decode_dim(const int* p) {
  int v = p[0];
  if (v > 0 && v < 1000000) return (double)v;
  return (double)__int_as_float(v);
}

// ==== zero hist/hist2/sValid/sBoxD/sup/mOut — after heads (aliases featF) ===
__global__ void zero_kernel(unsigned* __restrict__ hist, unsigned* __restrict__ hist2,
                            int* __restrict__ sValid, double* __restrict__ sBoxD,
                            unsigned long long* __restrict__ sup,
                            unsigned* __restrict__ mOut)
{
  const int i = blockIdx.x * 256 + threadIdx.x;
  if (i < 262144) { hist[i] = 0u; hist2[i] = 0u; }
  if (i < 12000) sValid[i] = 0;
  if (i < 48000) sBoxD[i] = 0.0;
  if (i < 4) mOut[i] = 0u;
  for (size_t k = i; k < 565504; k += 262144) sup[k] = 0ull;  // 4*47*3008
}

// ======================= anchors + loc2bbox + clip + valid + fg (f64) ========
// R26: histogram atomics wave-aggregated.
__global__ void prep_kernel(const double* __restrict__ locD,
                            const double* __restrict__ scoreD,
                            const int* __restrict__ img_h_p, const int* __restrict__ img_w_p,
                            double* __restrict__ roiD, double* __restrict__ selD,
                            unsigned* __restrict__ hist, float* __restrict__ d_out)
{
  const int i = blockIdx.x * 256 + threadIdx.x;
  const int n = blockIdx.y;
  if (i >= 22500) return;
  const int p = i / 9, ab = i - p * 9;
  const int y = p / 50, x = p - y * 50;
  const int ri = ab / 3, sidx = ab - ri * 3;
  const double rr = (ri == 0) ? 0.5 : (ri == 1 ? 1.0 : 2.0);
  const double sc = (sidx == 0) ? 8.0 : (sidx == 1 ? 16.0 : 32.0);
  const double hh = 16.0 * sc * sqrt(rr);
  const double wd = 16.0 * sc * sqrt(1.0 / rr);
  const float bx1 = (float)(8.0 - wd * 0.5), by1 = (float)(8.0 - hh * 0.5);
  const float bx2 = (float)(8.0 + wd * 0.5), by2 = (float)(8.0 + hh * 0.5);
  const float sxf = (float)(x * 16), syf = (float)(y * 16);
  const float ax1 = bx1 + sxf, ay1 = by1 + syf, ax2 = bx2 + sxf, ay2 = by2 + syf;
  if (n == 0) {
    ((float4*)(d_out + 546000))[i] = make_float4(ax1, ay1, ax2, ay2);
  }
  const double l0 = locD[(size_t)n * 90000 + (size_t)i * 4 + 0];
  const double l1 = locD[(size_t)n * 90000 + (size_t)i * 4 + 1];
  const double l2 = locD[(size_t)n * 90000 + (size_t)i * 4 + 2];
  const double l3 = locD[(size_t)n * 90000 + (size_t)i * 4 + 3];
  const double s0 = scoreD[(size_t)n * 45000 + (size_t)i * 2 + 0];
  const double s1 = scoreD[(size_t)n * 45000 + (size_t)i * 2 + 1];
  const double aw = (double)ax2 - (double)ax1, ah = (double)ay2 - (double)ay1;
  const double acx = (double)ax1 + 0.5 * aw, acy = (double)ay1 + 0.5 * ah;
  const double cx = l0 * aw + acx, cy = l1 * ah + acy;
  const double ww = exp(l2) * aw, hh2 = exp(l3) * ah;
  double x1 = cx - 0.5 * ww, y1 = cy - 0.5 * hh2;
  double x2 = cx + 0.5 * ww, y2 = cy + 0.5 * hh2;
  const double fw = decode_dim(img_w_p), fh = decode_dim(img_h_p);
  x1 = fmin(fmax(x1, 0.0), fw); x2 = fmin(fmax(x2, 0.0), fw);
  y1 = fmin(fmax(y1, 0.0), fh); y2 = fmin(fmax(y2, 0.0), fh);
  const bool valid = (x2 - x1 + 1.0 >= 16.0) && (y2 - y1 + 1.0 >= 16.0);
  const double m = fmax(s0, s1);
  const double e0 = exp(s0 - m), e1 = exp(s1 - m);
  const double fg = e1 / (e0 + e1);
  double* rb = roiD + ((size_t)n * 22500 + i) * 4;
  rb[0] = x1; rb[1] = y1; rb[2] = x2; rb[3] = y2;
  selD[(size_t)n * 22500 + i] = valid ? fg : -INFINITY;
  // fg in (0,1): positive f64 -> bits order == value order
  const unsigned key = (unsigned)((unsigned long long)__double_as_longlong(fg) >> 48);
  const int lane = threadIdx.x & 63;
  unsigned long long act = __ballot(valid);
  while (act) {
    const int leader = __ffsll(act) - 1;
    const unsigned k0 = (unsigned)__shfl((int)key, leader);
    const unsigned long long same = __ballot(valid && key == k0);
    if (lane == leader)
      atomicAdd(&hist[n * 65536 + k0], (unsigned)__popcll(same));
    act &= ~same;
  }
}

// ======================= threshold L1: largest key covering top-3000 ========
// R28 form: per-thread contiguous sums (cache-line reuse, pipelined loads).
__global__ __launch_bounds__(256) void thresh_kernel(
    const unsigned* __restrict__ hist, unsigned* __restrict__ thrP,
    unsigned* __restrict__ cntAbove)
{
  const int n = blockIdx.x;
  const int t = threadIdx.x;
  __shared__ unsigned csum[256];
  __shared__ unsigned hv[256];
  __shared__ int cstar;
  __shared__ unsigned sufS;
  const unsigned* h = hist + (size_t)n * 65536;
  unsigned s = 0;
  for (int k = 0; k < 256; k++) s += h[t * 256 + k];
  csum[t] = s;
  __syncthreads();
  if (t == 0) {
    unsigned suf = 0; int cs = -1;
    for (int c = 255; c >= 0; c--) {
      if (suf + csum[c] >= 3000u) { cs = c; break; }
      suf += csum[c];
    }
    cstar = cs; sufS = suf;
  }
  __syncthreads();
  const int cs = cstar;
  if (cs >= 0) hv[t] = h[cs * 256 + t];
  __syncthreads();
  if (t == 0) {
    unsigned Tkey = 0, above = 0;
    if (cs >= 0) {
      unsigned suf = sufS;
      for (int v = 255; v >= 0; v--) {
        if (suf + hv[v] >= 3000u) { Tkey = (unsigned)(cs * 256 + v); above = suf; break; }
        suf += hv[v];
      }
    }
    thrP[n] = Tkey;        // 0 if <3000 valid -> all valid become candidates
    cntAbove[n] = above;   // strictly < 3000 by construction
  }
}

// ============ L2 refinement: histogram bits 47:32 within threshold class ====
__global__ void hist2_kernel(const double* __restrict__ selD,
                             const unsigned* __restrict__ thrP,
                             unsigned* __restrict__ hist2)
{
  const int i = blockIdx.x * 256 + threadIdx.x;
  const int n = blockIdx.y;
  if (i >= 22500) return;
  double s = selD[(size_t)n * 22500 + i];
  if (!(s > -INFINITY)) return;
  unsigned long long b = (unsigned long long)__double_as_longlong(s);
  if ((unsigned)(b >> 48) == thrP[n]) {
    unsigned key2 = (unsigned)(b >> 32) & 0xFFFFu;
    atomicAdd(&hist2[n * 65536 + key2], 1u);   // keys well-spread: low contention
  }
}

// thresh2: largest key2 s.t. cntAbove + suffix2 >= 3000 (0 if class empty)
__global__ __launch_bounds__(256) void thresh2_kernel(
    const unsigned* __restrict__ hist2, const unsigned* __restrict__ cntAbove,
    unsigned* __restrict__ thr2P)
{
  const int n = blockIdx.x;
  const int t = threadIdx.x;
  __shared__ unsigned csum[256];
  __shared__ unsigned hv[256];
  __shared__ int cstar;
  __shared__ unsigned sufS;
  const unsigned* h = hist2 + (size_t)n * 65536;
  const unsigned target = 3000u - cntAbove[n];   // >= 1
  unsigned s = 0;
  for (int k = 0; k < 256; k++) s += h[t * 256 + k];
  csum[t] = s;
  __syncthreads();
  if (t == 0) {
    unsigned suf = 0; int cs = -1;
    for (int c = 255; c >= 0; c--) {
      if (suf + csum[c] >= target) { cs = c; break; }
      suf += csum[c];
    }
    cstar = cs; sufS = suf;
  }
  __syncthreads();
  const int cs = cstar;
  if (cs >= 0) hv[t] = h[cs * 256 + t];
  __syncthreads();
  if (t == 0) {
    unsigned T2 = 0;
    if (cs >= 0) {
      unsigned suf = sufS;
      for (int v = 255; v >= 0; v--) {
        suf += hv[v];
        if (suf >= target) { T2 = (unsigned)(cs * 256 + v); break; }
      }
    }
    thr2P[n] = T2;   // 0 if class can't reach target (e.g. <3000 valid total)
  }
}

// ============ deterministic 2-phase compaction (no blkOff kernel) ===========
__device__ inline bool cand_flag(const double* __restrict__ selD,
                                 const unsigned* __restrict__ thrP,
                                 const unsigned* __restrict__ thr2P,
                                 int n, int i, double* sOut) {
  double s = selD[(size_t)n * 22500 + i];
  *sOut = s;
  if (!(s > -INFINITY)) return false;
  unsigned long long b = (unsigned long long)__double_as_longlong(s);
  unsigned key = (unsigned)(b >> 48);
  unsigned T = thrP[n];
  if (key != T) return key > T;
  return ((unsigned)(b >> 32) & 0xFFFFu) >= thr2P[n];
}

// phase 1: per-block candidate counts + mOut accumulation (R29).
// mOut = sum of integer block totals via atomicAdd: order-independent.
__global__ __launch_bounds__(256) void ccount_kernel(
    const double* __restrict__ selD, const unsigned* __restrict__ thrP,
    const unsigned* __restrict__ thr2P, unsigned* __restrict__ blkCnt,
    unsigned* __restrict__ mOut)
{
  const int i = blockIdx.x * 256 + threadIdx.x;
  const int n = blockIdx.y;
  double s;
  bool f = (i < 22500) && cand_flag(selD, thrP, thr2P, n, i, &s);
  unsigned long long b = __ballot(f);
  __shared__ unsigned wc[4];
  const int wv = threadIdx.x >> 6, lane = threadIdx.x & 63;
  if (lane == 0) wc[wv] = (unsigned)__popcll(b);
  __syncthreads();
  if (threadIdx.x == 0) {
    unsigned tot = wc[0] + wc[1] + wc[2] + wc[3];
    blkCnt[n * 88 + blockIdx.x] = tot;
    atomicAdd(&mOut[n], tot);
  }
}

// phase 2 (R29): scatter with block-prefix computed locally per wave from
// L2-resident blkCnt (masked loads + shfl_xor reduce). Exact integer sum ->
// positions bit-identical to the old cscan+blkOff path.
__global__ __launch_bounds__(256) void cscatter_kernel(
    const double* __restrict__ selD, const unsigned* __restrict__ thrP,
    const unsigned* __restrict__ thr2P, const unsigned* __restrict__ blkCnt,
    int* __restrict__ candIdx, double* __restrict__ candS)
{
  const int i = blockIdx.x * 256 + threadIdx.x;
  const int n = blockIdx.y;
  double s = 0.0;
  bool f = (i < 22500) && cand_flag(selD, thrP, thr2P, n, i, &s);
  unsigned long long b = __ballot(f);
  const int wv = threadIdx.x >> 6, lane = threadIdx.x & 63;
  __shared__ unsigned wc[4];
  if (lane == 0) wc[wv] = (unsigned)__popcll(b);
  // block-exclusive prefix over blkCnt[n*88 + 0..blockIdx.x-1]
  unsigned pv0 = (lane < (int)blockIdx.x) ? blkCnt[n * 88 + lane] : 0u;
  unsigned pv1 = (64 + lane < (int)blockIdx.x) ? blkCnt[n * 88 + 64 + lane] : 0u;
  unsigned boff = pv0 + pv1;
  #pragma unroll
  for (int off = 1; off < 64; off <<= 1)
    boff += (unsigned)__shfl_xor((int)boff, off);
  __syncthreads();
  unsigned woff = 0;
  for (int w = 0; w < wv; w++) woff += wc[w];
  unsigned lpre = (unsigned)__popcll(b & ((1ull << lane) - 1ull));
  if (f) {
    unsigned pos = boff + woff + lpre;
    candIdx[(size_t)n * 22500 + pos] = i;
    candS[(size_t)n * 22500 + pos] = s;
  }
}

// ============ exact rank among candidates, j-axis split 12 ways =============
#define RCHUNKS 12
#define RSTRIDE 22528

__global__ __launch_bounds__(256) void crank1_kernel(
    const unsigned* __restrict__ mOut, const int* __restrict__ candIdx,
    const double* __restrict__ candS, int* __restrict__ partialR)
{
  const int n = blockIdx.z;
  const int m = (int)mOut[n];
  if ((int)(blockIdx.x * 256) >= m) return;   // block-uniform early exit
  const int c = blockIdx.y;
  const int tid = blockIdx.x * 256 + threadIdx.x;
  const bool act = (tid < m);
  const double si = act ? candS[(size_t)n * 22500 + tid] : 0.0;
  const int ii = act ? candIdx[(size_t)n * 22500 + tid] : 0x7fffffff;
  const int jlo = (int)(((long long)c * m) / RCHUNKS);
  const int jhi = (int)(((long long)(c + 1) * m) / RCHUNKS);
  __shared__ double sv[256];
  __shared__ int siv[256];
  int rank = 0;
  for (int j0 = jlo; j0 < jhi; j0 += 256) {
    __syncthreads();
    const int jl = j0 + threadIdx.x;
    if (jl < jhi) {
      sv[threadIdx.x] = candS[(size_t)n * 22500 + jl];
      siv[threadIdx.x] = candIdx[(size_t)n * 22500 + jl];
    }
    __syncthreads();
    const int lim = (jhi - j0 < 256) ? (jhi - j0) : 256;
    #pragma unroll 8
    for (int k = 0; k < lim; k++) {
      const double sj = sv[k];
      const int ij = siv[k];
      rank += ((sj > si) || (sj == si && ij < ii)) ? 1 : 0;
    }
  }
  if (act) partialR[((size_t)n * RCHUNKS + c) * RSTRIDE + tid] = rank;
}

__global__ __launch_bounds__(256) void crank2_kernel(
    const unsigned* __restrict__ mOut, const int* __restrict__ candIdx,
    const int* __restrict__ partialR, const double* __restrict__ roiD,
    double* __restrict__ sBoxD, int* __restrict__ sValid)
{
  const int n = blockIdx.y;
  const int m = (int)mOut[n];
  const int tid = blockIdx.x * 256 + threadIdx.x;
  if (tid >= m) return;
  int rank = 0;
  #pragma unroll
  for (int c = 0; c < RCHUNKS; c++)
    rank += partialR[((size_t)n * RCHUNKS + c) * RSTRIDE + tid];
  if (rank < 3000) {
    const int ii = candIdx[(size_t)n * 22500 + tid];
    const double* rb = roiD + ((size_t)n * 22500 + ii) * 4;
    double* db = sBoxD + ((size_t)n * 3000 + rank) * 4;
    db[0] = rb[0]; db[1] = rb[1]; db[2] = rb[2]; db[3] = rb[3];
    sValid[n * 3000 + rank] = 1;
  }
}

// ======================= NMS phase A: suppression bitmask (f64 IoU) ==========
// sup layout WORD-MAJOR (R25). R29: below-diagonal words are pre-zeroed by
// zero_kernel; those blocks return WITHOUT storing.
__global__ void supmat_kernel(const double* __restrict__ sBoxD,
                              unsigned long long* __restrict__ sup)
{
  const int wj = blockIdx.x, ig = blockIdx.y, n = blockIdx.z;
  const int lane = threadIdx.x;
  const int i = ig * 64 + lane;
  if (wj < ig) return;                 // pre-zeroed by zero_kernel (R29)
  unsigned long long* dst = sup + ((size_t)n * 47 + wj) * 3008;
  __shared__ double jb[64][4];
  const int j0 = wj * 64;
  {
    int j = j0 + lane;
    if (j < 3000) {
      const double* b = sBoxD + ((size_t)n * 3000 + j) * 4;
      jb[lane][0] = b[0]; jb[lane][1] = b[1]; jb[lane][2] = b[2]; jb[lane][3] = b[3];
    } else {
      jb[lane][0] = 0; jb[lane][1] = 0; jb[lane][2] = 0; jb[lane][3] = 0;
    }
  }
  __syncthreads();
  if (i >= 3000) return;
  const double* bi = sBoxD + ((size_t)n * 3000 + i) * 4;
  const double bx1 = bi[0], by1 = bi[1], bx2 = bi[2], by2 = bi[3];
  const double ai = (bx2 - bx1) * (by2 - by1);
  unsigned long long msk = 0;
  #pragma unroll 2
  for (int tt = 0; tt < 64; tt++) {
    const int j = j0 + tt;
    const double jx1 = jb[tt][0], jy1 = jb[tt][1], jx2 = jb[tt][2], jy2 = jb[tt][3];
    double iw = fmax(fmin(bx2, jx2) - fmax(bx1, jx1), 0.0);
    double ih = fmax(fmin(by2, jy2) - fmax(by1, jy1), 0.0);
    double inter = iw * ih;
    double aj = (jx2 - jx1) * (jy2 - jy1);
    double iou = inter / (ai + aj - inter + 1e-9);
    if (iou > 0.7 && j > i && j < 3000) msk |= (1ull << tt);
  }
  dst[i] = msk;
}

// ======================= NMS phase B: alive-only scan, early stop at 300 =====
__global__ __launch_bounds__(64) void nms_scan_kernel(
    const double* __restrict__ sBoxD,
    const int* __restrict__ sValid,
    const unsigned long long* __restrict__ sup,
    float* __restrict__ out)
{
  const int n = blockIdx.x;
  const int lane = threadIdx.x;
  unsigned long long alive = 0;
  for (int w = 0; w < 47; w++) {
    int idx = w * 64 + lane;
    int v = (idx < 3000) ? sValid[(size_t)n * 3000 + idx] : 0;
    unsigned long long bm = __ballot(v != 0);
    if (lane == w) alive = bm;
  }
  const unsigned long long* sbase = sup + (size_t)n * 47 * 3008;

  __shared__ unsigned long long rows[2][64][49];
  __shared__ int keptIdx[304];
  unsigned long long stg[47];

  auto STAGE_LOAD = [&](int w) {
    const unsigned long long* src = sbase + w * 64 + lane;
    #pragma unroll
    for (int k = 0; k < 47; k++) stg[k] = src[(size_t)k * 3008];
  };
  auto STAGE_WRITE = [&](int buf) {
    #pragma unroll
    for (int k = 0; k < 47; k++) rows[buf][lane][k] = stg[k];
  };

  STAGE_LOAD(0);
  STAGE_WRITE(0);
  __syncthreads();
  STAGE_LOAD(1);

  int kept = 0;
  for (int w = 0; w < 47 && kept < 300; w++) {
    const int buf = w & 1;
    unsigned long long t = __shfl(alive, w);
    while (t != 0ull && kept < 300) {
      const int b = __ffsll(t) - 1;
      const int i = w * 64 + b;
      unsigned long long row = (lane < 47) ? rows[buf][b][lane] : 0ull;
      alive &= ~row;
      if (lane == 0) keptIdx[kept] = i;    // ds_write: off the serial chain
      kept++;
      const unsigned long long hi = (b == 63) ? 0ull : (~0ull << (b + 1));
      t = __shfl(alive, w) & hi;
    }
    if (w + 1 < 47) {
      STAGE_WRITE(buf ^ 1);
      __syncthreads();
      if (w + 2 < 47) STAGE_LOAD(w + 2);
    }
  }
  __syncthreads();                         // keptIdx visible to all lanes

  float4* rois4 = (float4*)(out + 540000);
  for (int r = lane; r < kept; r += 64) {
    const int i = keptIdx[r];
    const double* bb = sBoxD + ((size_t)n * 3000 + i) * 4;
    rois4[n * 300 + r] = make_float4((float)bb[0], (float)bb[1],
                                     (float)bb[2], (float)bb[3]);
  }
  for (int k = kept + lane; k < 300; k += 64)
    rois4[n * 300 + k] = make_float4(0, 0, 0, 0);
  for (int k = lane; k < 300; k += 64)
    out[544800 + n * 300 + k] = (float)n;
}

// ======================= launch =======================
extern "C" void kernel_launch(void* const* d_in, const int* in_sizes, int n_in,
                              void* d_out, int out_size, void* d_ws, size_t ws_size,
                              hipStream_t stream) {
  const float* x        = (const float*)d_in[0];
  const float* conv1_w  = (const float*)d_in[1];
  const float* conv1_b  = (const float*)d_in[2];
  const float* loc_w    = (const float*)d_in[3];
  const float* loc_b    = (const float*)d_in[4];
  const float* score_w  = (const float*)d_in[5];
  const float* score_b  = (const float*)d_in[6];
  const int*   img_h    = (const int*)d_in[7];
  const int*   img_w    = (const int*)d_in[8];
  float* out = (float*)d_out;
  char* ws = (char*)d_ws;

  float*    featF = (float*)(ws);                       // [0, 20,480,000)
  _Float16* Whi   = (_Float16*)(ws + 20480000);         // +4,718,592
  _Float16* Wlo   = (_Float16*)(ws + 25198592);         // +4,718,592
  float*    Xt    = (float*)(ws + 29917184);            // +10,240,000 -> 40,157,184
  double*   locD   = (double*)(ws + 20480000);          // +2,880,000 (over Whi, dead)
  double*   scoreD = (double*)(ws + 23360000);          // +1,440,000 -> 24,800,000
  double* roiD   = (double*)(ws);                  // [0, 2,880,000)
  double* selD   = (double*)(ws + 2880000);        // +720,000
  double* sBoxD  = (double*)(ws + 3600000);        // +384,000
  int*    sValid = (int*)(ws + 4000000);           // +48,000
  unsigned long long* sup = (unsigned long long*)(ws + 4100000);  // +4,524,032 (word-major) -> 8,624,032
  unsigned* hist   = (unsigned*)(ws + 8700000);    // +1,048,576
  unsigned* blkCnt = (unsigned*)(ws + 9750000);    // +1,408
  unsigned* mOut   = (unsigned*)(ws + 9754000);    // +16
  unsigned* thrP   = (unsigned*)(ws + 9755000);    // +16
  unsigned* cntAb  = (unsigned*)(ws + 9756000);    // +16
  unsigned* thr2P  = (unsigned*)(ws + 9757000);    // +16
  int*      candIdx= (int*)(ws + 9760000);         // +360,000
  double*   candS  = (double*)(ws + 10200000);     // +720,000 -> 10,920,000
  unsigned* hist2  = (unsigned*)(ws + 10920000);   // +1,048,576 -> 11,968,576
  int*      partialR = (int*)(ws + 12000000);      // +4,325,376 -> 16,325,376

  prepin_kernel<<<712, 256, 0, stream>>>(conv1_w, Whi, Wlo, x, Xt);
  conv_f16_kernel<<<dim3(50, 2, 4), 256, 0, stream>>>(Xt, Whi, Wlo, conv1_b, featF);
  heads_kernel<<<dim3(10, 7, 4), 256, 0, stream>>>(featF, loc_w, loc_b, score_w, score_b,
                                                   locD, scoreD, out);
  zero_kernel<<<1024, 256, 0, stream>>>(hist, hist2, sValid, sBoxD, sup, mOut);
  prep_kernel<<<dim3(88, 4), 256, 0, stream>>>(locD, scoreD, img_h, img_w,
                                               roiD, selD, hist, out);
  thresh_kernel<<<4, 256, 0, stream>>>(hist, thrP, cntAb);
  hist2_kernel<<<dim3(88, 4), 256, 0, stream>>>(selD, thrP, hist2);
  thresh2_kernel<<<4, 256, 0, stream>>>(hist2, cntAb, thr2P);
  ccount_kernel<<<dim3(88, 4), 256, 0, stream>>>(selD, thrP, thr2P, blkCnt, mOut);
  cscatter_kernel<<<dim3(88, 4), 256, 0, stream>>>(selD, thrP, thr2P, blkCnt, candIdx, candS);
  crank1_kernel<<<dim3(88, RCHUNKS, 4), 256, 0, stream>>>(mOut, candIdx, candS, partialR);
  crank2_kernel<<<dim3(88, 4), 256, 0, stream>>>(mOut, candIdx, partialR, roiD, sBoxD, sValid);
  supmat_kernel<<<dim3(47, 47, 4), 64, 0, stream>>>(sBoxD, sup);
  nms_scan_kernel<<<4, 64, 0, stream>>>(sBoxD, sValid, sup, out);
}